// Round 19
// baseline (174.690 us; speedup 1.0000x reference)
//
#include <hip/hip_runtime.h>
#include <math.h>

#define BN 16384

typedef float f32x4 __attribute__((ext_vector_type(4)));
typedef short bf16x8v __attribute__((ext_vector_type(8)));
typedef unsigned short u16x8 __attribute__((ext_vector_type(8)));
typedef unsigned short u16x4 __attribute__((ext_vector_type(4)));

static __device__ inline unsigned short f2bf(float f) {
  unsigned u = __float_as_uint(f);
  return (unsigned short)((u + 0x8000u) >> 16);
}
static __device__ inline float bf2f(unsigned short u) {
  return __uint_as_float(((unsigned)u) << 16);
}

// bank-conflict-free slot swizzle: rows at 64B stride, 4x16B slots
#define XS(r) (((r) >> 1) & 3)

// ---------------- workspace float offsets ----------------
#define WKA_OFF   0
#define WVA_OFF   8192
#define WKE_OFF   16384
#define WVE_OFF   24576
#define WKEF_OFF  32768
#define BKA_OFF   40960
#define BVA_OFF   41216
#define BKE_OFF   41472
#define BVE_OFF   41728
#define BKEF_OFF  41984
#define WMP_OFF   43008
#define BMP_OFF   44544
#define G_OFF     45056
#define BG_OFF    53248
#define WQB_OFF   53312
#define SC0_OFF   53568
#define BMG_OFF   53632
#define CLB_OFF   53888
#define BPJA_OFF  57088
#define BPJE_OFF  57344
#define BGRU_OFF  57600
#define BHD_OFF   16384

#define QSRC_OFF  65536            /* pal bf16 lives here (shorts) */
#define BUF1_OFF  (QSRC_OFF + BN*256)
#define BUF2_OFF  (BUF1_OFF + BN*256)
#define BUF3_OFF  (BUF2_OFF + BN*256)
#define BUF4_OFF  (BUF3_OFF + BN*256)
#define BUF5_OFF  (BUF4_OFF + BN*256)

#define GBUF_OFF  BUF1_OFF   // g bf16 (shorts); WF overwrites after core2
#define AOUTA_OFF BUF3_OFF   // bf16 shorts
#define AOUTE_OFF BUF4_OFF   // bf16 shorts
#define GBB_OFF   BUF5_OFF
#define UB_OFF    (BUF5_OFF + 8388608)

#define HOFF      (BN*22)

// bf16 weight cache in d_out's h-region
#define MGB_S 0
#define CLA_S 65536
#define CLE_S 196608
#define PJA_S 327680
#define PJE_S 360448

// ---------------- fuseA (2-way parallel fold) ----------------
__global__ __launch_bounds__(256) void k_fuseA(
    const float* __restrict__ attnA_W, const float* __restrict__ attnA_b,
    const float* __restrict__ attnE_W, const float* __restrict__ attnE_b,
    const float* __restrict__ W_ally,  const float* __restrict__ b_ally,
    const float* __restrict__ W_enemy, const float* __restrict__ b_enemy,
    const float* __restrict__ Wke,     const float* __restrict__ bke,
    const float* __restrict__ clnA_W,  const float* __restrict__ clnE_W,
    float* __restrict__ FW, unsigned short* __restrict__ WBc) {
  int g = blockIdx.x * 256 + threadIdx.x;
  if (g < 81920) {
    int u = g >> 1, t = g & 1;
    int m = u >> 13;
    int r = u & 8191;
    int d = r >> 5, j = r & 31;
    const float *Wout, *Win, *bin, *bout; float *dst, *dstb;
    switch (m) {
      case 0: Wout = attnA_W + 65536;  Win = W_ally;  bin = b_ally;  bout = attnA_b + 256; dst = FW + WKA_OFF;  dstb = FW + BKA_OFF;  break;
      case 1: Wout = attnA_W + 131072; Win = W_ally;  bin = b_ally;  bout = attnA_b + 512; dst = FW + WVA_OFF;  dstb = FW + BVA_OFF;  break;
      case 2: Wout = attnE_W + 65536;  Win = W_enemy; bin = b_enemy; bout = attnE_b + 256; dst = FW + WKE_OFF;  dstb = FW + BKE_OFF;  break;
      case 3: Wout = attnE_W + 131072; Win = W_enemy; bin = b_enemy; bout = attnE_b + 512; dst = FW + WVE_OFF;  dstb = FW + BVE_OFF;  break;
      default:Wout = Wke;              Win = W_enemy; bin = b_enemy; bout = bke;           dst = FW + WKEF_OFF; dstb = FW + BKEF_OFF; break;
    }
    const int c0 = t * 128;
    float acc = 0.f;
    for (int c = c0; c < c0 + 128; ++c) acc += Wout[d*256 + c] * Win[c*32 + j];
    acc += __shfl_xor(acc, 1);
    if (t == 0) dst[d*32 + j] = acc;
    if (j == 0) {
      float b = 0.f;
      for (int c = c0; c < c0 + 128; ++c) b += Wout[d*256 + c] * bin[c];
      b += __shfl_xor(b, 1);
      if (t == 0) dstb[d] = b + bout[d];
    }
  } else {
    int t = g - 81920;
    if (t < 65536) {
      int e = t * 4;
      const float* src = (e < 131072) ? clnA_W : clnE_W;
      int off = (e < 131072) ? 0 : 131072;
      float4 v = *(const float4*)(src + (e - off));
      u16x4 b; b.x = f2bf(v.x); b.y = f2bf(v.y); b.z = f2bf(v.z); b.w = f2bf(v.w);
      *(u16x4*)&WBc[CLA_S + e] = b;
    }
  }
}

// ---------------- fuseB (2-way parallel on 256-deep section) ----------------
__global__ __launch_bounds__(256) void k_fuseB(
    const float* __restrict__ protos, const float* __restrict__ Wmq,
    const float* __restrict__ bmq,    const float* __restrict__ Wqs,
    const float* __restrict__ bqs,
    const float* __restrict__ attnA_W, const float* __restrict__ attnA_b,
    const float* __restrict__ attnE_W, const float* __restrict__ attnE_b,
    const float* __restrict__ clnA_b,  const float* __restrict__ clnE_b,
    float* __restrict__ FW, unsigned short* __restrict__ WBc) {
  int g = blockIdx.x * 256 + threadIdx.x;
  const float* WKe_f = FW + WKEF_OFF;
  const float* bKe_f = FW + BKEF_OFF;
  if (g < 20480) {
    int u = g >> 1, tt = g & 1;
    const int c0 = tt * 128;
    if (u < 1536) {
      int i = u >> 8, c = u & 255;
      float acc = 0.f;
      for (int d = c0; d < c0 + 128; ++d) acc += protos[i*256 + d] * Wmq[d*256 + c];
      acc += __shfl_xor(acc, 1);
      if (tt == 0) FW[WMP_OFF + i*256 + c] = acc;
    } else if (u < 9728) {
      int r = u - 1536;
      int j = r >> 8, c = r & 255;
      float acc = 0.f;
      for (int d = c0; d < c0 + 128; ++d) acc += WKe_f[d*32 + j] * Wqs[d*256 + c];
      acc += __shfl_xor(acc, 1);
      if (tt == 0) FW[G_OFF + j*256 + c] = acc;
    } else if (u < 9984) {
      int c = u - 9728;
      float acc = 0.f;
      for (int d = c0; d < c0 + 128; ++d) acc += Wqs[d*256 + c] * bKe_f[d];
      acc += __shfl_xor(acc, 1);
      if (tt == 0) FW[WQB_OFF + c] = acc;
    } else if (u < 9990) {
      int i = u - 9984;
      float acc = 0.f;
      for (int d = c0; d < c0 + 128; ++d) acc += protos[i*256 + d] * bmq[d];
      acc += __shfl_xor(acc, 1);
      if (tt == 0) FW[BMP_OFF + i] = acc;
    } else if (u < 10022) {
      int j = u - 9990;
      float acc = 0.f;
      for (int d = c0; d < c0 + 128; ++d) acc += WKe_f[d*32 + j] * bqs[d];
      acc += __shfl_xor(acc, 1);
      if (tt == 0) FW[BG_OFF + j] = acc;
    } else if (u == 10022) {
      float acc = 0.f;
      for (int d = c0; d < c0 + 128; ++d) acc += bqs[d] * bKe_f[d];
      acc += __shfl_xor(acc, 1);
      if (tt == 0) FW[SC0_OFF] = acc;
    }
  } else if (g < 87296) {
    int t = g - 20480;
    if (t < 65536) {
      int r = t >> 8, c = t & 255;
      int br = r >> 7, jj = r & 127, h = jj >> 5, jc = jj & 31;
      const float* W0 = br ? attnE_W : attnA_W;
      const float* Wk = FW + (br ? WKE_OFF : WKA_OFF);
      float acc = 0.f;
      for (int d = 0; d < 64; ++d)
        acc += W0[(h*64+d)*256 + c] * Wk[(h*64+d)*32 + jc];
      WBc[MGB_S + r*256 + c] = f2bf(acc);
    } else if (t < 65792) {
      int r = t - 65536;
      int br = r >> 7, jj = r & 127, h = jj >> 5, jc = jj & 31;
      const float* b0 = br ? attnE_b : attnA_b;
      const float* Wk = FW + (br ? WKE_OFF : WKA_OFF);
      float acc = 0.f;
      for (int d = 0; d < 64; ++d) acc += b0[h*64+d] * Wk[(h*64+d)*32 + jc];
      FW[BMG_OFF + r] = acc;
    } else {
      int c = t - 65792;
      FW[CLB_OFF + c] = (c < 512) ? clnA_b[c] : clnE_b[c - 512];
    }
  } else {
    int t = g - 87296;
    if (t < 65536) {
      int br = t >> 15;
      int r0 = t & 32767;
      int o = r0 >> 7, r = r0 & 127, h = r >> 5, j = r & 31;
      const float* Wp = (br ? attnE_W : attnA_W) + 196608;
      const float* Wv = FW + (br ? WVE_OFF : WVA_OFF);
      float acc = 0.f;
      for (int d = 0; d < 64; ++d)
        acc += Wp[o*256 + h*64 + d] * Wv[(h*64+d)*32 + j];
      WBc[(br ? PJE_S : PJA_S) + o*128 + r] = f2bf(acc);
    } else if (t < 66048) {
      int r0 = t - 65536;
      int br = r0 >> 8, c = r0 & 255;
      const float* Wp = (br ? attnE_W : attnA_W) + 196608;
      const float* bv = FW + (br ? BVE_OFF : BVA_OFF);
      const float* pb = (br ? attnE_b : attnA_b) + 768;
      float acc = pb[c];
      for (int d = 0; d < 256; ++d) acc += Wp[c*256 + d] * bv[d];
      FW[(br ? BPJE_OFF : BPJA_OFF) + c] = acc;
    }
  }
}

// ---------------- heads fold ----------------
__global__ __launch_bounds__(256) void k_fuse4(
    const float* __restrict__ Wv_head, const float* __restrict__ bv_head,
    const float* __restrict__ Wtb, const float* __restrict__ btb,
    float* __restrict__ FW, unsigned short* __restrict__ WHD) {
  int g = blockIdx.x * 256 + threadIdx.x;
  if (g < 32768) {
    int r = g >> 8, c = g & 255;
    float v;
    if (r == 0)       v = Wv_head[c];
    else if (r == 1)  v = Wtb[c];
    else if (r == 2)  v = Wtb[256 + c];
    else if (r < 9)   v = FW[WMP_OFF + (r - 3) * 256 + c];
    else if (r < 41)  v = FW[G_OFF + (r - 9) * 256 + c];
    else if (r == 41) v = FW[WQB_OFF + c];
    else              v = 0.f;
    WHD[r * 256 + c] = f2bf(v);
  } else if (g < 32896) {
    int r = g - 32768;
    float v;
    if (r == 0)       v = bv_head[0];
    else if (r == 1)  v = btb[0];
    else if (r == 2)  v = btb[1];
    else if (r < 9)   v = FW[BMP_OFF + r - 3];
    else if (r < 41)  v = FW[BG_OFF + r - 9];
    else if (r == 41) v = FW[SC0_OFF];
    else              v = 0.f;
    FW[BHD_OFF + r] = v;
  }
}

// ---------------- GRU weight fold v2: FRAGMENT-ORDER layout ----------------
__global__ __launch_bounds__(256) void k_gruw2(
    const float* __restrict__ Wih, const float* __restrict__ Whh,
    const float* __restrict__ bih, const float* __restrict__ bhh,
    unsigned short* __restrict__ WF, float* __restrict__ BG) {
  int t = blockIdx.x * 256 + threadIdx.x;
  if (t < 131072) {
    int l = t & 63;
    int n = (t >> 6) & 3;
    int cq = (t >> 8) & 3;
    int bx = (t >> 10) & 3;
    int ch = t >> 12;
    int lr = l & 15, lk = l >> 4;
    int d = bx * 64 + cq * 16 + lr;
    int kb = ch * 32 + lk * 8;
    float fa[8];
    bool zero = (kb < 768) ? (n == 3) : (n == 2);
    if (zero) {
      #pragma unroll
      for (int i = 0; i < 8; ++i) fa[i] = 0.f;
    } else if (kb < 768) {
      const float* src = Wih + (long)(n * 256 + d) * 768 + kb;
      *(float4*)&fa[0] = *(const float4*)(src);
      *(float4*)&fa[4] = *(const float4*)(src + 4);
    } else {
      int rh = (n == 3 ? 512 : n * 256) + d;
      const float* src = Whh + (long)rh * 256 + (kb - 768);
      *(float4*)&fa[0] = *(const float4*)(src);
      *(float4*)&fa[4] = *(const float4*)(src + 4);
    }
    u16x8 pk;
    #pragma unroll
    for (int i = 0; i < 8; ++i) pk[i] = f2bf(fa[i]);
    *(u16x8*)&WF[(long)t * 8] = pk;
  } else if (t < 132096) {
    int p = t - 131072;
    int X = p >> 8, df = (p >> 6) & 3, g = (p >> 4) & 3, i = p & 15;
    int d = X * 64 + df * 16 + i;
    float v;
    if (g == 0)      v = bih[d] + bhh[d];
    else if (g == 1) v = bih[256 + d] + bhh[256 + d];
    else if (g == 2) v = bih[512 + d];
    else             v = bhh[512 + d];
    BG[p] = v;
  }
}

// ---------------- small-K dense (K=30) -> bf16 qsrc ----------------
template<int K, int NOUT>
__global__ __launch_bounds__(256) void k_densek(
    const float* __restrict__ A, const float* __restrict__ W,
    const float* __restrict__ bias, unsigned short* __restrict__ Cb) {
  constexpr int KB = 32;
  __shared__ float As[64][36];
  const int tid = threadIdx.x;
  const int s0 = blockIdx.x * 64;
  const int o0 = blockIdx.y * 64;
  const int ox = (tid & 15) * 4;
  const int sy = (tid >> 4) * 4;
  float acc[4][4] = {};
  const float* Abase = A + (long)s0 * K;
  for (int idx = tid; idx < 64 * KB; idx += 256) {
    int s = idx >> 5, c = idx & 31;
    As[s][c] = (c < K) ? Abase[(long)s * K + c] : 0.f;
  }
  __syncthreads();
  for (int kk = 0; kk < KB; kk += 4) {
    float a4[4][4];
    #pragma unroll
    for (int sj = 0; sj < 4; ++sj)
      *(float4*)a4[sj] = *(const float4*)&As[sy + sj][kk];
    #pragma unroll
    for (int oi = 0; oi < 4; ++oi) {
      float w4[4];
      #pragma unroll
      for (int kx = 0; kx < 4; ++kx) {
        int k = kk + kx;
        w4[kx] = (k < K) ? W[(long)(o0 + ox + oi) * K + k] : 0.f;
      }
      #pragma unroll
      for (int sj = 0; sj < 4; ++sj)
        #pragma unroll
        for (int kx = 0; kx < 4; ++kx)
          acc[sj][oi] = fmaf(a4[sj][kx], w4[kx], acc[sj][oi]);
    }
  }
  #pragma unroll
  for (int sj = 0; sj < 4; ++sj) {
    u16x4 b4;
    b4.x = f2bf(acc[sj][0] + bias[o0 + ox + 0]);
    b4.y = f2bf(acc[sj][1] + bias[o0 + ox + 1]);
    b4.z = f2bf(acc[sj][2] + bias[o0 + ox + 2]);
    b4.w = f2bf(acc[sj][3] + bias[o0 + ox + 3]);
    *(u16x4*)&Cb[(long)(s0 + sy + sj) * NOUT + o0 + ox] = b4;
  }
}

// ---- shared MFMA machinery (swizzle XS both sides) ----
#define MM_PROLOG(GDX)                                                        \
  __shared__ __align__(16) unsigned short As[4096];                           \
  __shared__ __align__(16) unsigned short Ws[4096];                           \
  const int tid = threadIdx.x;                                                \
  const int pid = blockIdx.y * (GDX) + blockIdx.x;                            \
  const int bx = (pid >> 3) % (GDX);                                          \
  const int by = ((pid >> 3) / (GDX)) * 8 + (pid & 7);                        \
  const long s0 = (long)by * 128;                                             \
  const int wv = tid >> 6, l = tid & 63;                                      \
  const int wm = (wv >> 1) * 64, wn = (wv & 1) * 64;                          \
  const int lr = l & 15, lk = l >> 4;                                         \
  const int wrow = tid >> 2;                                                  \
  const int wslot = tid & 3;                                                  \
  (void)wrow; (void)wslot;                                                    \
  f32x4 acc[4][4] = {};

#define MM_MFMA_STEP                                                          \
  {                                                                           \
    bf16x8v af[4], bw[4];                                                     \
    _Pragma("unroll")                                                         \
    for (int m = 0; m < 4; ++m) {                                             \
      const int r = wm + m * 16 + lr;                                         \
      af[m] = *(const bf16x8v*)&As[r * 32 + ((lk ^ XS(r)) * 8)];              \
    }                                                                         \
    _Pragma("unroll")                                                         \
    for (int n = 0; n < 4; ++n) {                                             \
      const int r = wn + n * 16 + lr;                                         \
      bw[n] = *(const bf16x8v*)&Ws[r * 32 + ((lk ^ XS(r)) * 8)];              \
    }                                                                         \
    _Pragma("unroll")                                                         \
    for (int m = 0; m < 4; ++m)                                               \
      _Pragma("unroll")                                                       \
      for (int n = 0; n < 4; ++n)                                             \
        acc[m][n] = __builtin_amdgcn_mfma_f32_16x16x32_bf16(af[m], bw[n], acc[m][n], 0, 0, 0); \
  }

// ---------------- merged qsrc GEMM: 1280 outs -> g bf16 + gb bf16 ----------------
__global__ __launch_bounds__(256) void k_mm_qs(
    const unsigned short* __restrict__ Abf, const unsigned short* __restrict__ W,
    const float* __restrict__ bias, unsigned short* __restrict__ Cg,
    unsigned short* __restrict__ Cgb) {
  MM_PROLOG(10)
  const int o0 = bx * 128;
  u16x8 pw[2], pa_b[2];
  const unsigned short* Wb = W + (long)o0 * 256;
  #pragma unroll
  for (int p = 0; p < 2; ++p) {
    const int r = wrow + 64 * p;
    pw[p]   = *(const u16x8*)(Wb + (long)r * 256 + wslot * 8);
    pa_b[p] = *(const u16x8*)(Abf + (s0 + r) * 256 + wslot * 8);
  }
  for (int ch = 0; ch < 8; ++ch) {
    if (ch) __syncthreads();
    #pragma unroll
    for (int p = 0; p < 2; ++p) {
      const int r = wrow + 64 * p;
      const int ps = (wslot ^ XS(r)) * 8;
      *(u16x8*)&Ws[r * 32 + ps] = pw[p];
      *(u16x8*)&As[r * 32 + ps] = pa_b[p];
    }
    __syncthreads();
    if (ch + 1 < 8) {
      const int k0 = (ch + 1) * 32;
      #pragma unroll
      for (int p = 0; p < 2; ++p) {
        const int r = wrow + 64 * p;
        pw[p]   = *(const u16x8*)(Wb + (long)r * 256 + k0 + wslot * 8);
        pa_b[p] = *(const u16x8*)(Abf + (s0 + r) * 256 + k0 + wslot * 8);
      }
    }
    MM_MFMA_STEP
  }
  if (bx < 2) {
    const int ob = bx * 128;
    #pragma unroll
    for (int n = 0; n < 4; ++n) {
      const float b = bias[o0 + wn + n * 16 + lr];
      #pragma unroll
      for (int m = 0; m < 4; ++m) {
        const long rowb = s0 + wm + m * 16 + lk * 4;
        #pragma unroll
        for (int r = 0; r < 4; ++r)
          Cg[(rowb + r) * 256 + ob + wn + n * 16 + lr] = f2bf(acc[m][n][r] + b);
      }
    }
  } else {
    const int ob = (bx - 2) * 128;
    #pragma unroll
    for (int n = 0; n < 4; ++n) {
      const float b = bias[o0 + wn + n * 16 + lr];
      #pragma unroll
      for (int m = 0; m < 4; ++m) {
        const long rowb = s0 + wm + m * 16 + lk * 4;
        #pragma unroll
        for (int r = 0; r < 4; ++r)
          Cgb[(rowb + r) * 1024 + ob + wn + n * 16 + lr] = f2bf(acc[m][n][r] + b);
      }
    }
  }
}

// ---------------- merged pal@PV GEMM (bf16 out) ----------------
__global__ __launch_bounds__(256) void k_mm_pv(
    const unsigned short* __restrict__ pal, const unsigned short* __restrict__ W,
    const float* __restrict__ bias, unsigned short* __restrict__ CA,
    unsigned short* __restrict__ CE) {
  MM_PROLOG(4)
  const int o0 = bx * 128;
  const int br = bx >> 1;
  const unsigned short* Abf = pal + br * 128;
  u16x8 pw[2], pa_b[2];
  const unsigned short* Wb = W + (long)o0 * 128;
  #pragma unroll
  for (int p = 0; p < 2; ++p) {
    const int r = wrow + 64 * p;
    pw[p]   = *(const u16x8*)(Wb + (long)r * 128 + wslot * 8);
    pa_b[p] = *(const u16x8*)(Abf + (s0 + r) * 256 + wslot * 8);
  }
  for (int ch = 0; ch < 4; ++ch) {
    if (ch) __syncthreads();
    #pragma unroll
    for (int p = 0; p < 2; ++p) {
      const int r = wrow + 64 * p;
      const int ps = (wslot ^ XS(r)) * 8;
      *(u16x8*)&Ws[r * 32 + ps] = pw[p];
      *(u16x8*)&As[r * 32 + ps] = pa_b[p];
    }
    __syncthreads();
    if (ch + 1 < 4) {
      const int k0 = (ch + 1) * 32;
      #pragma unroll
      for (int p = 0; p < 2; ++p) {
        const int r = wrow + 64 * p;
        pw[p]   = *(const u16x8*)(Wb + (long)r * 128 + k0 + wslot * 8);
        pa_b[p] = *(const u16x8*)(Abf + (s0 + r) * 256 + k0 + wslot * 8);
      }
    }
    MM_MFMA_STEP
  }
  unsigned short* C = br ? CE : CA;
  const int ob = (bx & 1) * 128;
  #pragma unroll
  for (int n = 0; n < 4; ++n) {
    const float b = bias[o0 + wn + n * 16 + lr];
    #pragma unroll
    for (int m = 0; m < 4; ++m) {
      const long rowb = s0 + wm + m * 16 + lk * 4;
      #pragma unroll
      for (int r = 0; r < 4; ++r)
        C[(rowb + r) * 256 + ob + wn + n * 16 + lr] = f2bf(acc[m][n][r] + b);
    }
  }
}

// ---------------- GRU mega-GEMM v10: 64x256 tile, 4 waves, W fragments direct ----------------
__global__ __launch_bounds__(256, 4) void k_gru10(
    const unsigned short* __restrict__ UB, const float* __restrict__ hid,
    const unsigned short* __restrict__ WF, const float* __restrict__ BG,
    float* __restrict__ hout) {
  __shared__ __align__(16) unsigned short As[2][2048];   // 2 x 64 x 32
  const int tid = threadIdx.x;                        // 0..255
  const int pid = blockIdx.y * 4 + blockIdx.x;        // grid (4,256)
  const int lin = pid >> 3;
  const int bx = lin & 3;
  const int by = (lin >> 2) * 8 + (pid & 7);          // 0..255
  const long s0 = (long)by * 64;
  const int wv = tid >> 6, l = tid & 63;
  const int cq = wv;                                  // col quad (== df)
  const int lr = l & 15, lk = l >> 4;
  const int row = tid >> 2;                           // 0..63
  const int q = tid & 3;

  f32x4 acc[4][4] = {};
  u16x8 bwc0, bwc1, bwc2, bwn0, bwn1, bwn2;
  u16x8 pa_b;
  float4 pa_f[2];

  // fragment base for (ch, n): WF + (((ch*4+bx)*4+cq)*4+n)*512 + l*8
  const unsigned short* WFb = WF + (((long)bx * 4 + cq) * 4) * 512 + l * 8;
#define WFRAG(CH, N) (*(const u16x8*)(WFb + ((long)(CH) * 64 + (N)) * 512))

#define GRU10_MFMA(G0, G1, G2)                                                \
  {                                                                           \
    const unsigned short* AsC = As[cur];                                      \
    bf16x8v af[4];                                                            \
    _Pragma("unroll")                                                         \
    for (int m = 0; m < 4; ++m) {                                             \
      const int r = m * 16 + lr;                                              \
      af[m] = *(const bf16x8v*)&AsC[r * 32 + ((lk ^ XS(r)) * 8)];             \
    }                                                                         \
    _Pragma("unroll")                                                         \
    for (int m = 0; m < 4; ++m) {                                             \
      acc[m][G0] = __builtin_amdgcn_mfma_f32_16x16x32_bf16(af[m], (bf16x8v)bwc0, acc[m][G0], 0, 0, 0); \
      acc[m][G1] = __builtin_amdgcn_mfma_f32_16x16x32_bf16(af[m], (bf16x8v)bwc1, acc[m][G1], 0, 0, 0); \
      acc[m][G2] = __builtin_amdgcn_mfma_f32_16x16x32_bf16(af[m], (bf16x8v)bwc2, acc[m][G2], 0, 0, 0); \
    }                                                                         \
  }

  // prologue: A chunk0 -> As[0]; W frags chunk0 (gates 0,1,2)
  pa_b = *(const u16x8*)(UB + (s0 + row) * 768 + q * 8);
  *(u16x8*)&As[0][row * 32 + ((q ^ XS(row)) * 8)] = pa_b;
  bwc0 = WFRAG(0, 0); bwc1 = WFRAG(0, 1); bwc2 = WFRAG(0, 2);
  __syncthreads();

  // u-part chunks (0..23): gates {0,1,2}
  for (int ch = 0; ch < 24; ++ch) {
    const int cur = ch & 1;
    const int k0 = (ch + 1) * 32;
    if (ch + 1 < 24) {
      pa_b = *(const u16x8*)(UB + (s0 + row) * 768 + k0 + q * 8);
      bwn0 = WFRAG(ch + 1, 0); bwn1 = WFRAG(ch + 1, 1); bwn2 = WFRAG(ch + 1, 2);
    } else {
      const float* Af = hid + (s0 + row) * 256 + q * 8;
      pa_f[0] = *(const float4*)(Af);
      pa_f[1] = *(const float4*)(Af + 4);
      bwn0 = WFRAG(24, 0); bwn1 = WFRAG(24, 1); bwn2 = WFRAG(24, 3);
    }
    GRU10_MFMA(0, 1, 2)
    if (ch + 1 < 24) {
      *(u16x8*)&As[cur ^ 1][row * 32 + ((q ^ XS(row)) * 8)] = pa_b;
    } else {
      float fa[8];
      *(float4*)&fa[0] = pa_f[0];
      *(float4*)&fa[4] = pa_f[1];
      u16x8 pk;
      #pragma unroll
      for (int i = 0; i < 8; ++i) pk[i] = f2bf(fa[i]);
      *(u16x8*)&As[cur ^ 1][row * 32 + ((q ^ XS(row)) * 8)] = pk;
    }
    __syncthreads();
    bwc0 = bwn0; bwc1 = bwn1; bwc2 = bwn2;
  }
  // hid-part chunks (24..31): gates {0,1,3}
  for (int ch = 24; ch < 32; ++ch) {
    const int cur = ch & 1;
    if (ch + 1 < 32) {
      const int k0 = (ch + 1) * 32;
      const int km = k0 - 768;
      const float* Af = hid + (s0 + row) * 256 + km + q * 8;
      pa_f[0] = *(const float4*)(Af);
      pa_f[1] = *(const float4*)(Af + 4);
      bwn0 = WFRAG(ch + 1, 0); bwn1 = WFRAG(ch + 1, 1); bwn2 = WFRAG(ch + 1, 3);
    }
    GRU10_MFMA(0, 1, 3)
    if (ch + 1 < 32) {
      float fa[8];
      *(float4*)&fa[0] = pa_f[0];
      *(float4*)&fa[4] = pa_f[1];
      u16x8 pk;
      #pragma unroll
      for (int i = 0; i < 8; ++i) pk[i] = f2bf(fa[i]);
      *(u16x8*)&As[cur ^ 1][row * 32 + ((q ^ XS(row)) * 8)] = pk;
      __syncthreads();
      bwc0 = bwn0; bwc1 = bwn1; bwc2 = bwn2;
    }
  }

  // epilogue: acc[m][g], wave covers d = bx*64 + cq*16 + lr
  const int d = bx * 64 + cq * 16 + lr;
  const int bb = bx * 256 + cq * 64 + lr;
  const float bR  = BG[bb];
  const float bZ  = BG[bb + 16];
  const float bNi = BG[bb + 32];
  const float bNh = BG[bb + 48];
  #pragma unroll
  for (int m = 0; m < 4; ++m) {
    const long srow = s0 + m * 16 + lk * 4;
    #pragma unroll
    for (int rr = 0; rr < 4; ++rr) {
      const long s = srow + rr;
      const float r_ = 1.f / (1.f + expf(-(acc[m][0][rr] + bR)));
      const float z_ = 1.f / (1.f + expf(-(acc[m][1][rr] + bZ)));
      const float n_ = tanhf(acc[m][2][rr] + bNi + r_ * (acc[m][3][rr] + bNh));
      const float hp = hid[s * 256 + d];
      hout[s * 256 + d] = (1.f - z_) * n_ + z_ * hp;
    }
  }
#undef GRU10_MFMA
#undef WFRAG
}

// ---------------- merged attention core (g bf16) ----------------
__global__ __launch_bounds__(256) void k_core2(
    const float* __restrict__ rawA, const float* __restrict__ rawE,
    const unsigned short* __restrict__ g, const float* __restrict__ gt_w,
    const float* __restrict__ gt_b, unsigned short* __restrict__ pal) {
  __shared__ float A_[4][15][36];
  __shared__ float E_[4][16][36];
  __shared__ float G_[4][8][32];
  __shared__ float P_[4][8][16];
  const int tid = threadIdx.x;
  const int w = tid >> 6, l = tid & 63;
  const long s = (long)blockIdx.x * 4 + w;

  const float* ra = rawA + s * 480;
  const float* re = rawE + s * 512;
  const unsigned short* gr = g + s * 256;
  #pragma unroll
  for (int i = l; i < 120; i += 64) {
    float4 v = *(const float4*)(ra + i * 4);
    *(float4*)&A_[w][i >> 3][(i & 7) * 4] = v;
  }
  #pragma unroll
  for (int i = l; i < 128; i += 64) {
    float4 v = *(const float4*)(re + i * 4);
    *(float4*)&E_[w][i >> 3][(i & 7) * 4] = v;
  }
  {
    u16x4 v = *(const u16x4*)(gr + l * 4);
    float4 f = { bf2f(v.x), bf2f(v.y), bf2f(v.z), bf2f(v.w) };
    *(float4*)&G_[w][l >> 3][(l & 7) * 4] = f;
  }
  __syncthreads();

  bool mv = false;
  if (l < 15) {
    #pragma unroll
    for (int c = 0; c < 8; ++c) {
      float4 x = *(const float4*)&A_[w][l][c * 4];
      mv |= (x.x != 0.f) | (x.y != 0.f) | (x.z != 0.f) | (x.w != 0.f);
    }
  } else if (l >= 16 && l < 32) {
    #pragma unroll
    for (int c = 0; c < 8; ++c) {
      float4 x = *(const float4*)&E_[w][l - 16][c * 4];
      mv |= (x.x != 0.f) | (x.y != 0.f) | (x.z != 0.f) | (x.w != 0.f);
    }
  }
  unsigned long long bal = __ballot(mv);
  unsigned mA = (unsigned)bal & 0x7FFFu;
  unsigned mE = (unsigned)(bal >> 16) & 0xFFFFu;
  float xa = gt_w[0] * log1pf((float)__popc(mA)) + gt_b[0];
  float spa = fmaxf(xa, 0.f) + log1pf(expf(-fabsf(xa)));
  float scaleA = 1.f / (8.f * (spa + 1.f));
  float xe = gt_w[1] * log1pf((float)__popc(mE)) + gt_b[1];
  float spe = fmaxf(xe, 0.f) + log1pf(expf(-fabsf(xe)));
  float scaleE = 1.f / (8.f * (spe + 1.f));

  {
    const int h = l >> 4, n = l & 15;
    const bool okA = (n < 15) && ((mA >> n) & 1);
    const bool okE = (mE >> n) & 1;
    const float* arow = &A_[w][n < 15 ? n : 0][0];
    const float* erow = &E_[w][n][0];
    const float* garow = &G_[w][h][0];
    const float* gerow = &G_[w][4 + h][0];
    float accA = 0.f, accE = 0.f;
    #pragma unroll
    for (int j = 0; j < 32; ++j) {
      accA = fmaf(garow[j], arow[j], accA);
      accE = fmaf(gerow[j], erow[j], accE);
    }
    float sA = okA ? accA * scaleA : -INFINITY;
    float sE = okE ? accE * scaleE : -INFINITY;
    float mAx = sA, mEx = sE;
    #pragma unroll
    for (int off = 8; off; off >>= 1) {
      mAx = fmaxf(mAx, __shfl_xor(mAx, off));
      mEx = fmaxf(mEx, __shfl_xor(mEx, off));
    }
    float eA = okA ? expf(sA - mAx) : 0.f;
    float eE = okE ? expf(sE - mEx) : 0.f;
    float suA = eA, suE = eE;
    #pragma unroll
    for (int off = 8; off; off >>= 1) {
      suA += __shfl_xor(suA, off);
      suE += __shfl_xor(suE, off);
    }
    P_[w][h][n] = eA / suA;
    P_[w][4 + h][n] = eE / suE;
  }
  __syncthreads();

  {
    const int j = l & 31, hh = l >> 5;
    unsigned short* po = pal + s * 256 + hh * 32 + j;
    #pragma unroll
    for (int r = 0; r < 2; ++r) {
      const int ha = r * 2 + hh;
      float a0 = 0.f, a1 = 0.f;
      #pragma unroll
      for (int n = 0; n < 15; ++n)
        a0 = fmaf(P_[w][ha][n], A_[w][n][j], a0);
      #pragma unroll
      for (int n = 0; n < 16; ++n)
        a1 = fmaf(P_[w][4 + ha][n], E_[w][n][j], a1);
      po[r * 64] = f2bf(a0);
      po[128 + r * 64] = f2bf(a1);
    }
  }
}

// ---------------- fused CLN+CLN+LN3 -> u (all bf16 inputs) ----------------
__global__ __launch_bounds__(256) void k_clnln(
    const unsigned short* __restrict__ aA, const unsigned short* __restrict__ aE,
    const unsigned short* __restrict__ qsb, const unsigned short* __restrict__ gbb,
    const float* __restrict__ g, const float* __restrict__ b,
    unsigned short* __restrict__ UB) {
  int w = threadIdx.x >> 6, l = threadIdx.x & 63;
  long s = (long)blockIdx.x * 4 + w;
  int d = l * 4;
  u16x4 av = *(const u16x4*)(aA + s * 256 + d);
  u16x4 ev = *(const u16x4*)(aE + s * 256 + d);
  u16x4 qv = *(const u16x4*)(qsb + s * 256 + d);
  float4 vA = { bf2f(av.x), bf2f(av.y), bf2f(av.z), bf2f(av.w) };
  float4 vE = { bf2f(ev.x), bf2f(ev.y), bf2f(ev.z), bf2f(ev.w) };
  float4 vq = { bf2f(qv.x), bf2f(qv.y), bf2f(qv.z), bf2f(qv.w) };
  const unsigned short* gbr = gbb + s * 1024;
  float sumA = vA.x + vA.y + vA.z + vA.w;
  float ssqA = vA.x*vA.x + vA.y*vA.y + vA.z*vA.z + vA.w*vA.w;
  float sumE = vE.x + vE.y + vE.z + vE.w;
  float ssqE = vE.x*vE.x + vE.y*vE.y + vE.z*vE.z + vE.w*vE.w;
  #pragma unroll
  for (int off = 32; off > 0; off >>= 1) {
    sumA += __shfl_xor(sumA, off); ssqA += __shfl_xor(ssqA, off);
    sumE += __shfl_xor(sumE, off); ssqE += __shfl_xor(ssqE, off);
  }
  float muA = sumA * (1.f / 256.f);
  float rstdA = rsqrtf(ssqA * (1.f / 256.f) - muA * muA + 1e-5f);
  float muE = sumE * (1.f / 256.f);
  float rstdE = rsqrtf(ssqE * (1.f / 256.f) - muE * muE + 1e-5f);

  u16x4 u0 = *(const u16x4*)(gbr + d);
  u16x4 u1 = *(const u16x4*)(gbr + 256 + d);
  u16x4 u2 = *(const u16x4*)(gbr + 512 + d);
  u16x4 u3 = *(const u16x4*)(gbr + 768 + d);
  float4 gA4 = { bf2f(u0.x), bf2f(u0.y), bf2f(u0.z), bf2f(u0.w) };
  float4 bA4 = { bf2f(u1.x), bf2f(u1.y), bf2f(u1.z), bf2f(u1.w) };
  float4 gE4 = { bf2f(u2.x), bf2f(u2.y), bf2f(u2.z), bf2f(u2.w) };
  float4 bE4 = { bf2f(u3.x), bf2f(u3.y), bf2f(u3.z), bf2f(u3.w) };
  float4 zA, zE;
  zA.x = (1.f + gA4.x) * ((vA.x - muA) * rstdA) + bA4.x;
  zA.y = (1.f + gA4.y) * ((vA.y - muA) * rstdA) + bA4.y;
  zA.z = (1.f + gA4.z) * ((vA.z - muA) * rstdA) + bA4.z;
  zA.w = (1.f + gA4.w) * ((vA.w - muA) * rstdA) + bA4.w;
  zE.x = (1.f + gE4.x) * ((vE.x - muE) * rstdE) + bE4.x;
  zE.y = (1.f + gE4.y) * ((vE.y - muE) * rstdE) + bE4.y;
  zE.z = (1.f + gE4.z) * ((vE.z - muE) * rstdE) + bE4.z;
  zE.w = (1.f + gE4.w) * ((vE.w - muE) * rstdE) + bE4.w;

  float sum = vq.x+vq.y+vq.z+vq.w + zA.x+zA.y+zA.z+zA.w + zE.x+zE.y+zE.z+zE.w;
  float ssq = vq.x*vq.x+vq.y*vq.y+vq.z*vq.z+vq.w*vq.w
            + zA.x*zA.x+zA.y*zA.y+zA.z*zA.z+zA.w*zA.w
            + zE.x*zE.x+zE.y*zE.y+zE.z*zE.z+zE.w*zE.w;
  #pragma unroll
  for (int off = 32; off > 0; off >>= 1) {
    sum += __shfl_xor(sum, off); ssq += __shfl_xor(ssq, off);
  }
  float mu = sum * (1.f / 768.f);
  float rstd = rsqrtf(ssq * (1.f / 768.f) - mu * mu + 1e-5f);

  float4 g0 = *(const float4*)(g + d),       b0 = *(const float4*)(b + d);
  float4 g1 = *(const float4*)(g + 256 + d), b1 = *(const float4*)(b + 256 + d);
  float4 g2 = *(const float4*)(g + 512 + d), b2 = *(const float4*)(b + 512 + d);
  unsigned short* ur = UB + s * 768;
  u16x4 o;
  o.x = f2bf((vq.x - mu) * rstd * g0.x + b0.x);
  o.y = f2bf((vq.y - mu) * rstd * g0.y + b0.y);
  o.z = f2bf((vq.z - mu) * rstd * g0.z + b0.z);
  o.w = f2bf((vq.w - mu) * rstd * g0.w + b0.w);
  *(u16x4*)&ur[d] = o;
  o.x = f2bf((zA.x - mu) * rstd * g1.x + b1.x);
  o.y = f2bf((zA.y - mu) * rstd * g1.y + b1.y);
  o.z = f2bf((zA.z - mu) * rstd * g1.z + b1.z);
  o.w = f2bf((zA.w - mu) * rstd * g1.w + b1.w);
  *(u16x4*)&ur[256 + d] = o;
  o.x = f2bf((zE.x - mu) * rstd * g2.x + b2.x);
  o.y = f2bf((zE.y - mu) * rstd * g2.y + b2.y);
  o.z = f2bf((zE.z - mu) * rstd * g2.z + b2.z);
  o.w = f2bf((zE.w - mu) * rstd * g2.w + b2.w);
  *(u16x4*)&ur[512 + d] = o;
}

// ---------------- fused heads: 64-sample blocks ----------------
__global__ __launch_bounds__(256) void k_headsmm(
    const float* __restrict__ h, const unsigned short* __restrict__ WHD,
    const float* __restrict__ BHD, const float* __restrict__ eraw,
    const float* __restrict__ log_tau, float* __restrict__ Qout) {
  __shared__ __align__(16) unsigned short As[2048];   // 64 x 32
  __shared__ __align__(16) unsigned short Ws[2048];   // 64 x 32
  __shared__ float obs[64][49];
  const int tid = threadIdx.x;
  const long s0 = (long)blockIdx.x * 64;
  const int wv = tid >> 6, l = tid & 63;
  const int lr = l & 15, lk = l >> 4;
  const int row = tid >> 2;
  const int q = tid & 3;
  f32x4 acc[4] = {};
  u16x8 pw;
  float4 pa_f[2];
  pw = *(const u16x8*)(WHD + (long)row * 256 + q * 8);
  {
    const float* Af = h + (s0 + row) * 256 + q * 8;
    pa_f[0] = *(const float4*)(Af);
    pa_f[1] = *(const float4*)(Af + 4);
  }
  for (int ch = 0; ch < 8; ++ch) {
    if (ch) __syncthreads();
    *(u16x8*)&Ws[row * 32 + ((q ^ XS(row)) * 8)] = pw;
    {
      float fa[8];
      *(float4*)&fa[0] = pa_f[0];
      *(float4*)&fa[4] = pa_f[1];
      u16x8 pk;
      #pragma unroll
      for (int i = 0; i < 8; ++i) pk[i] = f2bf(fa[i]);
      *(u16x8*)&As[row * 32 + ((q ^ XS(row)) * 8)] = pk;
    }
    __syncthreads();
    if (ch + 1 < 8) {
      const int k0 = (ch + 1) * 32;
      pw = *(const u16x8*)(WHD + (long)row * 256 + k0 + q * 8);
      const float* Af = h + (s0 + row) * 256 + k0 + q * 8;
      pa_f[0] = *(const float4*)(Af);
      pa_f[1] = *(const float4*)(Af + 4);
    }
    {
      bf16x8v af, bw[4];
      {
        const int r = wv * 16 + lr;
        af = *(const bf16x8v*)&As[r * 32 + ((lk ^ XS(r)) * 8)];
      }
      #pragma unroll
      for (int n = 0; n < 4; ++n) {
        const int r = n * 16 + lr;
        bw[n] = *(const bf16x8v*)&Ws[r * 32 + ((lk ^ XS(r)) * 8)];
      }
      #pragma unroll
      for (int n = 0; n < 4; ++n)
        acc[n] = __builtin_amdgcn_mfma_f32_16x16x32_bf16(af, bw[n], acc[n], 0, 0, 0);
    }
  }
  #pragma unroll
  for (int n = 0; n < 3; ++n) {
    const int col = n * 16 + lr;
    const float b = BHD[col];
    const int rowo = wv * 16 + lk * 4;
    #pragma unroll
    for (int rr = 0; rr < 4; ++rr)
      obs[rowo + rr][col] = acc[n][rr] + b;
  }
  __syncthreads();
  const float itm = 1.f / (expf(log_tau[0]) + 1e-6f);
  const float its = 1.f / (expf(log_tau[1]) + 1e-6f);
  for (int rep = 0; rep < 4; ++rep) {
    const int sloc = rep * 16 + (tid >> 4);
    const int i = tid & 15;
    const long s = s0 + sloc;
    const float V = obs[sloc][0];
    const float* er = eraw + s * 512 + i * 32;
    bool valid = false; float a0 = 0.f;
    #pragma unroll
    for (int jb = 0; jb < 8; ++jb) {
      float4 e4 = *(const float4*)(er + jb * 4);
      valid |= (e4.x != 0.f) | (e4.y != 0.f) | (e4.z != 0.f) | (e4.w != 0.f);
      a0 += obs[sloc][9 + jb * 4 + 0] * e4.x + obs[sloc][9 + jb * 4 + 1] * e4.y +
            obs[sloc][9 + jb * 4 + 2] * e4.z + obs[sloc][9 + jb * 4 + 3] * e4.w;
    }
    float a = (a0 + obs[sloc][41]) * 0.0625f;
    float sa = valid ? a : 0.f;
    float cv = valid ? 1.f : 0.f;
    #pragma unroll
    for (int off = 8; off > 0; off >>= 1) {
      sa += __shfl_xor(sa, off);
      cv += __shfl_xor(cv, off);
    }
    float me = sa / fmaxf(cv, 1.f);
    Qout[s * 22 + 6 + i] = V + obs[sloc][2] + (valid ? (a - me) * its : -1e30f * its);
    if (i < 6) {
      float mean = 0.f;
      #pragma unroll
      for (int t = 0; t < 6; ++t) mean += obs[sloc][3 + t];
      mean *= (1.f / 6.f);
      Qout[s * 22 + i] = V + obs[sloc][1] + (obs[sloc][3 + i] - mean) * 0.0625f * itm;
    }
  }
}

// ---------------- launch ----------------
extern "C" void kernel_launch(void* const* d_in, const int* in_sizes, int n_in,
                              void* d_out, int out_size, void* d_ws, size_t ws_size,
                              hipStream_t stream) {
  const float* own_raw   = (const float*)d_in[0];
  const float* ally_raw  = (const float*)d_in[1];
  const float* enemy_raw = (const float*)d_in[2];
  const float* hidden    = (const float*)d_in[3];
  const float* W_own     = (const float*)d_in[4];
  const float* b_own     = (const float*)d_in[5];
  const float* W_ally    = (const float*)d_in[6];
  const float* b_ally    = (const float*)d_in[7];
  const float* W_enemy   = (const float*)d_in[8];
  const float* b_enemy   = (const float*)d_in[9];
  const float* gt_w      = (const float*)d_in[10];
  const float* gt_b      = (const float*)d_in[11];
  const float* attnA_W   = (const float*)d_in[12];
  const float* attnA_b   = (const float*)d_in[13];
  const float* attnE_W   = (const float*)d_in[14];
  const float* attnE_b   = (const float*)d_in[15];
  const float* clnA_W    = (const float*)d_in[16];
  const float* clnA_b    = (const float*)d_in[17];
  const float* clnE_W    = (const float*)d_in[18];
  const float* clnE_b    = (const float*)d_in[19];
  const float* ln3_g     = (const float*)d_in[20];
  const float* ln3_b     = (const float*)d_in[21];
  const float* gru_Wih   = (const float*)d_in[22];
  const float* gru_Whh   = (const float*)d_in[23];
  const float* gru_bih   = (const float*)d_in[24];
  const float* gru_bhh   = (const float*)d_in[25];
  const float* Wv_head   = (const float*)d_in[26];
  const float* bv_head   = (const float*)d_in[27];
  const float* Wtb       = (const float*)d_in[28];
  const float* btb       = (const float*)d_in[29];
  const float* log_tau   = (const float*)d_in[30];
  const float* Wmq       = (const float*)d_in[31];
  const float* bmq       = (const float*)d_in[32];
  const float* protos    = (const float*)d_in[33];
  const float* Wqs       = (const float*)d_in[34];
  const float* bqs       = (const float*)d_in[35];
  const float* Wke       = (const float*)d_in[36];
  const float* bke       = (const float*)d_in[37];

  float* ws  = (float*)d_ws;
  float* out = (float*)d_out;
  float* hout = out + HOFF;
  unsigned short* WB   = (unsigned short*)hout;
  unsigned short* qsb  = (unsigned short*)(ws + BUF2_OFF);
  unsigned short* palb = (unsigned short*)(ws + QSRC_OFF);
  unsigned short* WHD  = (unsigned short*)ws;
  unsigned short* wfrag = (unsigned short*)(ws + BUF1_OFF);  // WF (after core2)
  unsigned short* gb16 = (unsigned short*)(ws + GBUF_OFF);   // g bf16
  unsigned short* aoA  = (unsigned short*)(ws + AOUTA_OFF);  // aout bf16
  unsigned short* aoE  = (unsigned short*)(ws + AOUTE_OFF);
  unsigned short* gbb  = (unsigned short*)(ws + GBB_OFF);
  unsigned short* ub   = (unsigned short*)(ws + UB_OFF);     // u bf16

  k_fuseA<<<576, 256, 0, stream>>>(attnA_W, attnA_b, attnE_W, attnE_b,
                                   W_ally, b_ally, W_enemy, b_enemy, Wke, bke,
                                   clnA_W, clnE_W, ws, WB);
  k_fuseB<<<599, 256, 0, stream>>>(protos, Wmq, bmq, Wqs, bqs,
                                   attnA_W, attnA_b, attnE_W, attnE_b,
                                   clnA_b, clnE_b, ws, WB);
  k_fuse4<<<129, 256, 0, stream>>>(Wv_head, bv_head, Wtb, btb, ws, WHD);

  // q_src bf16
  k_densek<30, 256><<<dim3(BN/64, 4), 256, 0, stream>>>(own_raw, W_own, b_own, qsb);

  // merged: g bf16 (256) + gamma/beta bf16 (1024)
  k_mm_qs<<<dim3(10, 128), 256, 0, stream>>>(qsb, WB, ws + BMG_OFF, gb16, gbb);

  // merged attention core -> pal (bf16)
  k_core2<<<BN/4, 256, 0, stream>>>(ally_raw, enemy_raw, gb16, gt_w, gt_b, palb);

  // GRU fragment-order weights (into BUF1, now dead)
  k_gruw2<<<516, 256, 0, stream>>>(gru_Wih, gru_Whh, gru_bih, gru_bhh,
                                   wfrag, ws + BGRU_OFF);

  // aout = pal @ PV + bpj (both branches, bf16 out)
  k_mm_pv<<<dim3(4, 128), 256, 0, stream>>>(palb, WB + PJA_S, ws + BPJA_OFF,
                                            aoA, aoE);

  // fused cln+cln+ln3 -> u bf16
  k_clnln<<<BN/4, 256, 0, stream>>>(aoA, aoE, qsb, gbb, ln3_g, ln3_b, ub);

  // GRU mega-GEMM v10 -> h (64-sample tiles, 4 blocks/CU, W fragments direct)
  k_gru10<<<dim3(4, 256), 256, 0, stream>>>(ub, hidden, wfrag, ws + BGRU_OFF, hout);

  // fused heads GEMM + epilogue -> Q
  k_headsmm<<<BN/64, 256, 0, stream>>>(hout, WHD, ws + BHD_OFF, enemy_raw,
                                       log_tau, out);
}

// Round 20
// 173.671 us; speedup vs baseline: 1.0059x; 1.0059x over previous
//
#include <hip/hip_runtime.h>
#include <math.h>

#define BN 16384

typedef float f32x4 __attribute__((ext_vector_type(4)));
typedef short bf16x8v __attribute__((ext_vector_type(8)));
typedef unsigned short u16x8 __attribute__((ext_vector_type(8)));
typedef unsigned short u16x4 __attribute__((ext_vector_type(4)));

static __device__ inline unsigned short f2bf(float f) {
  unsigned u = __float_as_uint(f);
  return (unsigned short)((u + 0x8000u) >> 16);
}
static __device__ inline float bf2f(unsigned short u) {
  return __uint_as_float(((unsigned)u) << 16);
}

// bank-conflict-free slot swizzle: rows at 64B stride, 4x16B slots
#define XS(r) (((r) >> 1) & 3)

// ---------------- workspace float offsets ----------------
#define WKA_OFF   0
#define WVA_OFF   8192
#define WKE_OFF   16384
#define WVE_OFF   24576
#define WKEF_OFF  32768
#define BKA_OFF   40960
#define BVA_OFF   41216
#define BKE_OFF   41472
#define BVE_OFF   41728
#define BKEF_OFF  41984
#define WMP_OFF   43008
#define BMP_OFF   44544
#define G_OFF     45056
#define BG_OFF    53248
#define WQB_OFF   53312
#define SC0_OFF   53568
#define BMG_OFF   53632
#define CLB_OFF   53888
#define BPJA_OFF  57088
#define BPJE_OFF  57344
#define BGRU_OFF  57600
#define BHD_OFF   16384

#define QSRC_OFF  65536            /* pal bf16 lives here (shorts) */
#define BUF1_OFF  (QSRC_OFF + BN*256)
#define BUF2_OFF  (BUF1_OFF + BN*256)
#define BUF3_OFF  (BUF2_OFF + BN*256)
#define BUF4_OFF  (BUF3_OFF + BN*256)
#define BUF5_OFF  (BUF4_OFF + BN*256)

#define GBUF_OFF  BUF1_OFF   // g bf16 (shorts); WF overwrites after core2
#define AOUTA_OFF BUF3_OFF   // bf16 shorts
#define AOUTE_OFF BUF4_OFF   // bf16 shorts
#define GBB_OFF   BUF5_OFF
#define UB_OFF    (BUF5_OFF + 8388608)

#define HOFF      (BN*22)

// bf16 weight cache in d_out's h-region
#define MGB_S 0
#define CLA_S 65536
#define CLE_S 196608
#define PJA_S 327680
#define PJE_S 360448

// ---------------- fuseA (2-way parallel fold) ----------------
__global__ __launch_bounds__(256) void k_fuseA(
    const float* __restrict__ attnA_W, const float* __restrict__ attnA_b,
    const float* __restrict__ attnE_W, const float* __restrict__ attnE_b,
    const float* __restrict__ W_ally,  const float* __restrict__ b_ally,
    const float* __restrict__ W_enemy, const float* __restrict__ b_enemy,
    const float* __restrict__ Wke,     const float* __restrict__ bke,
    const float* __restrict__ clnA_W,  const float* __restrict__ clnE_W,
    float* __restrict__ FW, unsigned short* __restrict__ WBc) {
  int g = blockIdx.x * 256 + threadIdx.x;
  if (g < 81920) {
    int u = g >> 1, t = g & 1;
    int m = u >> 13;
    int r = u & 8191;
    int d = r >> 5, j = r & 31;
    const float *Wout, *Win, *bin, *bout; float *dst, *dstb;
    switch (m) {
      case 0: Wout = attnA_W + 65536;  Win = W_ally;  bin = b_ally;  bout = attnA_b + 256; dst = FW + WKA_OFF;  dstb = FW + BKA_OFF;  break;
      case 1: Wout = attnA_W + 131072; Win = W_ally;  bin = b_ally;  bout = attnA_b + 512; dst = FW + WVA_OFF;  dstb = FW + BVA_OFF;  break;
      case 2: Wout = attnE_W + 65536;  Win = W_enemy; bin = b_enemy; bout = attnE_b + 256; dst = FW + WKE_OFF;  dstb = FW + BKE_OFF;  break;
      case 3: Wout = attnE_W + 131072; Win = W_enemy; bin = b_enemy; bout = attnE_b + 512; dst = FW + WVE_OFF;  dstb = FW + BVE_OFF;  break;
      default:Wout = Wke;              Win = W_enemy; bin = b_enemy; bout = bke;           dst = FW + WKEF_OFF; dstb = FW + BKEF_OFF; break;
    }
    const int c0 = t * 128;
    float acc = 0.f;
    for (int c = c0; c < c0 + 128; ++c) acc += Wout[d*256 + c] * Win[c*32 + j];
    acc += __shfl_xor(acc, 1);
    if (t == 0) dst[d*32 + j] = acc;
    if (j == 0) {
      float b = 0.f;
      for (int c = c0; c < c0 + 128; ++c) b += Wout[d*256 + c] * bin[c];
      b += __shfl_xor(b, 1);
      if (t == 0) dstb[d] = b + bout[d];
    }
  } else {
    int t = g - 81920;
    if (t < 65536) {
      int e = t * 4;
      const float* src = (e < 131072) ? clnA_W : clnE_W;
      int off = (e < 131072) ? 0 : 131072;
      float4 v = *(const float4*)(src + (e - off));
      u16x4 b; b.x = f2bf(v.x); b.y = f2bf(v.y); b.z = f2bf(v.z); b.w = f2bf(v.w);
      *(u16x4*)&WBc[CLA_S + e] = b;
    }
  }
}

// ---------------- fuseB (2-way parallel on 256-deep section) ----------------
__global__ __launch_bounds__(256) void k_fuseB(
    const float* __restrict__ protos, const float* __restrict__ Wmq,
    const float* __restrict__ bmq,    const float* __restrict__ Wqs,
    const float* __restrict__ bqs,
    const float* __restrict__ attnA_W, const float* __restrict__ attnA_b,
    const float* __restrict__ attnE_W, const float* __restrict__ attnE_b,
    const float* __restrict__ clnA_b,  const float* __restrict__ clnE_b,
    float* __restrict__ FW, unsigned short* __restrict__ WBc) {
  int g = blockIdx.x * 256 + threadIdx.x;
  const float* WKe_f = FW + WKEF_OFF;
  const float* bKe_f = FW + BKEF_OFF;
  if (g < 20480) {
    int u = g >> 1, tt = g & 1;
    const int c0 = tt * 128;
    if (u < 1536) {
      int i = u >> 8, c = u & 255;
      float acc = 0.f;
      for (int d = c0; d < c0 + 128; ++d) acc += protos[i*256 + d] * Wmq[d*256 + c];
      acc += __shfl_xor(acc, 1);
      if (tt == 0) FW[WMP_OFF + i*256 + c] = acc;
    } else if (u < 9728) {
      int r = u - 1536;
      int j = r >> 8, c = r & 255;
      float acc = 0.f;
      for (int d = c0; d < c0 + 128; ++d) acc += WKe_f[d*32 + j] * Wqs[d*256 + c];
      acc += __shfl_xor(acc, 1);
      if (tt == 0) FW[G_OFF + j*256 + c] = acc;
    } else if (u < 9984) {
      int c = u - 9728;
      float acc = 0.f;
      for (int d = c0; d < c0 + 128; ++d) acc += Wqs[d*256 + c] * bKe_f[d];
      acc += __shfl_xor(acc, 1);
      if (tt == 0) FW[WQB_OFF + c] = acc;
    } else if (u < 9990) {
      int i = u - 9984;
      float acc = 0.f;
      for (int d = c0; d < c0 + 128; ++d) acc += protos[i*256 + d] * bmq[d];
      acc += __shfl_xor(acc, 1);
      if (tt == 0) FW[BMP_OFF + i] = acc;
    } else if (u < 10022) {
      int j = u - 9990;
      float acc = 0.f;
      for (int d = c0; d < c0 + 128; ++d) acc += WKe_f[d*32 + j] * bqs[d];
      acc += __shfl_xor(acc, 1);
      if (tt == 0) FW[BG_OFF + j] = acc;
    } else if (u == 10022) {
      float acc = 0.f;
      for (int d = c0; d < c0 + 128; ++d) acc += bqs[d] * bKe_f[d];
      acc += __shfl_xor(acc, 1);
      if (tt == 0) FW[SC0_OFF] = acc;
    }
  } else if (g < 87296) {
    int t = g - 20480;
    if (t < 65536) {
      int r = t >> 8, c = t & 255;
      int br = r >> 7, jj = r & 127, h = jj >> 5, jc = jj & 31;
      const float* W0 = br ? attnE_W : attnA_W;
      const float* Wk = FW + (br ? WKE_OFF : WKA_OFF);
      float acc = 0.f;
      for (int d = 0; d < 64; ++d)
        acc += W0[(h*64+d)*256 + c] * Wk[(h*64+d)*32 + jc];
      WBc[MGB_S + r*256 + c] = f2bf(acc);
    } else if (t < 65792) {
      int r = t - 65536;
      int br = r >> 7, jj = r & 127, h = jj >> 5, jc = jj & 31;
      const float* b0 = br ? attnE_b : attnA_b;
      const float* Wk = FW + (br ? WKE_OFF : WKA_OFF);
      float acc = 0.f;
      for (int d = 0; d < 64; ++d) acc += b0[h*64+d] * Wk[(h*64+d)*32 + jc];
      FW[BMG_OFF + r] = acc;
    } else {
      int c = t - 65792;
      FW[CLB_OFF + c] = (c < 512) ? clnA_b[c] : clnE_b[c - 512];
    }
  } else {
    int t = g - 87296;
    if (t < 65536) {
      int br = t >> 15;
      int r0 = t & 32767;
      int o = r0 >> 7, r = r0 & 127, h = r >> 5, j = r & 31;
      const float* Wp = (br ? attnE_W : attnA_W) + 196608;
      const float* Wv = FW + (br ? WVE_OFF : WVA_OFF);
      float acc = 0.f;
      for (int d = 0; d < 64; ++d)
        acc += Wp[o*256 + h*64 + d] * Wv[(h*64+d)*32 + j];
      WBc[(br ? PJE_S : PJA_S) + o*128 + r] = f2bf(acc);
    } else if (t < 66048) {
      int r0 = t - 65536;
      int br = r0 >> 8, c = r0 & 255;
      const float* Wp = (br ? attnE_W : attnA_W) + 196608;
      const float* bv = FW + (br ? BVE_OFF : BVA_OFF);
      const float* pb = (br ? attnE_b : attnA_b) + 768;
      float acc = pb[c];
      for (int d = 0; d < 256; ++d) acc += Wp[c*256 + d] * bv[d];
      FW[(br ? BPJE_OFF : BPJA_OFF) + c] = acc;
    }
  }
}

// ---------------- heads fold ----------------
__global__ __launch_bounds__(256) void k_fuse4(
    const float* __restrict__ Wv_head, const float* __restrict__ bv_head,
    const float* __restrict__ Wtb, const float* __restrict__ btb,
    float* __restrict__ FW, unsigned short* __restrict__ WHD) {
  int g = blockIdx.x * 256 + threadIdx.x;
  if (g < 32768) {
    int r = g >> 8, c = g & 255;
    float v;
    if (r == 0)       v = Wv_head[c];
    else if (r == 1)  v = Wtb[c];
    else if (r == 2)  v = Wtb[256 + c];
    else if (r < 9)   v = FW[WMP_OFF + (r - 3) * 256 + c];
    else if (r < 41)  v = FW[G_OFF + (r - 9) * 256 + c];
    else if (r == 41) v = FW[WQB_OFF + c];
    else              v = 0.f;
    WHD[r * 256 + c] = f2bf(v);
  } else if (g < 32896) {
    int r = g - 32768;
    float v;
    if (r == 0)       v = bv_head[0];
    else if (r == 1)  v = btb[0];
    else if (r == 2)  v = btb[1];
    else if (r < 9)   v = FW[BMP_OFF + r - 3];
    else if (r < 41)  v = FW[BG_OFF + r - 9];
    else if (r == 41) v = FW[SC0_OFF];
    else              v = 0.f;
    FW[BHD_OFF + r] = v;
  }
}

// ---------------- GRU weight fold v2: FRAGMENT-ORDER layout ----------------
__global__ __launch_bounds__(256) void k_gruw2(
    const float* __restrict__ Wih, const float* __restrict__ Whh,
    const float* __restrict__ bih, const float* __restrict__ bhh,
    unsigned short* __restrict__ WF, float* __restrict__ BG) {
  int t = blockIdx.x * 256 + threadIdx.x;
  if (t < 131072) {
    int l = t & 63;
    int n = (t >> 6) & 3;
    int cq = (t >> 8) & 3;
    int bx = (t >> 10) & 3;
    int ch = t >> 12;
    int lr = l & 15, lk = l >> 4;
    int d = bx * 64 + cq * 16 + lr;
    int kb = ch * 32 + lk * 8;
    float fa[8];
    bool zero = (kb < 768) ? (n == 3) : (n == 2);
    if (zero) {
      #pragma unroll
      for (int i = 0; i < 8; ++i) fa[i] = 0.f;
    } else if (kb < 768) {
      const float* src = Wih + (long)(n * 256 + d) * 768 + kb;
      *(float4*)&fa[0] = *(const float4*)(src);
      *(float4*)&fa[4] = *(const float4*)(src + 4);
    } else {
      int rh = (n == 3 ? 512 : n * 256) + d;
      const float* src = Whh + (long)rh * 256 + (kb - 768);
      *(float4*)&fa[0] = *(const float4*)(src);
      *(float4*)&fa[4] = *(const float4*)(src + 4);
    }
    u16x8 pk;
    #pragma unroll
    for (int i = 0; i < 8; ++i) pk[i] = f2bf(fa[i]);
    *(u16x8*)&WF[(long)t * 8] = pk;
  } else if (t < 132096) {
    int p = t - 131072;
    int X = p >> 8, df = (p >> 6) & 3, g = (p >> 4) & 3, i = p & 15;
    int d = X * 64 + df * 16 + i;
    float v;
    if (g == 0)      v = bih[d] + bhh[d];
    else if (g == 1) v = bih[256 + d] + bhh[256 + d];
    else if (g == 2) v = bih[512 + d];
    else             v = bhh[512 + d];
    BG[p] = v;
  }
}

// ---------------- small-K dense (K=30) -> bf16 qsrc ----------------
template<int K, int NOUT>
__global__ __launch_bounds__(256) void k_densek(
    const float* __restrict__ A, const float* __restrict__ W,
    const float* __restrict__ bias, unsigned short* __restrict__ Cb) {
  constexpr int KB = 32;
  __shared__ float As[64][36];
  const int tid = threadIdx.x;
  const int s0 = blockIdx.x * 64;
  const int o0 = blockIdx.y * 64;
  const int ox = (tid & 15) * 4;
  const int sy = (tid >> 4) * 4;
  float acc[4][4] = {};
  const float* Abase = A + (long)s0 * K;
  for (int idx = tid; idx < 64 * KB; idx += 256) {
    int s = idx >> 5, c = idx & 31;
    As[s][c] = (c < K) ? Abase[(long)s * K + c] : 0.f;
  }
  __syncthreads();
  for (int kk = 0; kk < KB; kk += 4) {
    float a4[4][4];
    #pragma unroll
    for (int sj = 0; sj < 4; ++sj)
      *(float4*)a4[sj] = *(const float4*)&As[sy + sj][kk];
    #pragma unroll
    for (int oi = 0; oi < 4; ++oi) {
      float w4[4];
      #pragma unroll
      for (int kx = 0; kx < 4; ++kx) {
        int k = kk + kx;
        w4[kx] = (k < K) ? W[(long)(o0 + ox + oi) * K + k] : 0.f;
      }
      #pragma unroll
      for (int sj = 0; sj < 4; ++sj)
        #pragma unroll
        for (int kx = 0; kx < 4; ++kx)
          acc[sj][oi] = fmaf(a4[sj][kx], w4[kx], acc[sj][oi]);
    }
  }
  #pragma unroll
  for (int sj = 0; sj < 4; ++sj) {
    u16x4 b4;
    b4.x = f2bf(acc[sj][0] + bias[o0 + ox + 0]);
    b4.y = f2bf(acc[sj][1] + bias[o0 + ox + 1]);
    b4.z = f2bf(acc[sj][2] + bias[o0 + ox + 2]);
    b4.w = f2bf(acc[sj][3] + bias[o0 + ox + 3]);
    *(u16x4*)&Cb[(long)(s0 + sy + sj) * NOUT + o0 + ox] = b4;
  }
}

// ---- shared MFMA machinery (swizzle XS both sides) ----
#define MM_PROLOG(GDX)                                                        \
  __shared__ __align__(16) unsigned short As[4096];                           \
  __shared__ __align__(16) unsigned short Ws[4096];                           \
  const int tid = threadIdx.x;                                                \
  const int pid = blockIdx.y * (GDX) + blockIdx.x;                            \
  const int bx = (pid >> 3) % (GDX);                                          \
  const int by = ((pid >> 3) / (GDX)) * 8 + (pid & 7);                        \
  const long s0 = (long)by * 128;                                             \
  const int wv = tid >> 6, l = tid & 63;                                      \
  const int wm = (wv >> 1) * 64, wn = (wv & 1) * 64;                          \
  const int lr = l & 15, lk = l >> 4;                                         \
  const int wrow = tid >> 2;                                                  \
  const int wslot = tid & 3;                                                  \
  (void)wrow; (void)wslot;                                                    \
  f32x4 acc[4][4] = {};

#define MM_MFMA_STEP                                                          \
  {                                                                           \
    bf16x8v af[4], bw[4];                                                     \
    _Pragma("unroll")                                                         \
    for (int m = 0; m < 4; ++m) {                                             \
      const int r = wm + m * 16 + lr;                                         \
      af[m] = *(const bf16x8v*)&As[r * 32 + ((lk ^ XS(r)) * 8)];              \
    }                                                                         \
    _Pragma("unroll")                                                         \
    for (int n = 0; n < 4; ++n) {                                             \
      const int r = wn + n * 16 + lr;                                         \
      bw[n] = *(const bf16x8v*)&Ws[r * 32 + ((lk ^ XS(r)) * 8)];              \
    }                                                                         \
    _Pragma("unroll")                                                         \
    for (int m = 0; m < 4; ++m)                                               \
      _Pragma("unroll")                                                       \
      for (int n = 0; n < 4; ++n)                                             \
        acc[m][n] = __builtin_amdgcn_mfma_f32_16x16x32_bf16(af[m], bw[n], acc[m][n], 0, 0, 0); \
  }

// ---------------- merged qsrc GEMM: 1280 outs -> g bf16 + gb bf16 ----------------
__global__ __launch_bounds__(256) void k_mm_qs(
    const unsigned short* __restrict__ Abf, const unsigned short* __restrict__ W,
    const float* __restrict__ bias, unsigned short* __restrict__ Cg,
    unsigned short* __restrict__ Cgb) {
  MM_PROLOG(10)
  const int o0 = bx * 128;
  u16x8 pw[2], pa_b[2];
  const unsigned short* Wb = W + (long)o0 * 256;
  #pragma unroll
  for (int p = 0; p < 2; ++p) {
    const int r = wrow + 64 * p;
    pw[p]   = *(const u16x8*)(Wb + (long)r * 256 + wslot * 8);
    pa_b[p] = *(const u16x8*)(Abf + (s0 + r) * 256 + wslot * 8);
  }
  for (int ch = 0; ch < 8; ++ch) {
    if (ch) __syncthreads();
    #pragma unroll
    for (int p = 0; p < 2; ++p) {
      const int r = wrow + 64 * p;
      const int ps = (wslot ^ XS(r)) * 8;
      *(u16x8*)&Ws[r * 32 + ps] = pw[p];
      *(u16x8*)&As[r * 32 + ps] = pa_b[p];
    }
    __syncthreads();
    if (ch + 1 < 8) {
      const int k0 = (ch + 1) * 32;
      #pragma unroll
      for (int p = 0; p < 2; ++p) {
        const int r = wrow + 64 * p;
        pw[p]   = *(const u16x8*)(Wb + (long)r * 256 + k0 + wslot * 8);
        pa_b[p] = *(const u16x8*)(Abf + (s0 + r) * 256 + k0 + wslot * 8);
      }
    }
    MM_MFMA_STEP
  }
  if (bx < 2) {
    const int ob = bx * 128;
    #pragma unroll
    for (int n = 0; n < 4; ++n) {
      const float b = bias[o0 + wn + n * 16 + lr];
      #pragma unroll
      for (int m = 0; m < 4; ++m) {
        const long rowb = s0 + wm + m * 16 + lk * 4;
        #pragma unroll
        for (int r = 0; r < 4; ++r)
          Cg[(rowb + r) * 256 + ob + wn + n * 16 + lr] = f2bf(acc[m][n][r] + b);
      }
    }
  } else {
    const int ob = (bx - 2) * 128;
    #pragma unroll
    for (int n = 0; n < 4; ++n) {
      const float b = bias[o0 + wn + n * 16 + lr];
      #pragma unroll
      for (int m = 0; m < 4; ++m) {
        const long rowb = s0 + wm + m * 16 + lk * 4;
        #pragma unroll
        for (int r = 0; r < 4; ++r)
          Cgb[(rowb + r) * 1024 + ob + wn + n * 16 + lr] = f2bf(acc[m][n][r] + b);
      }
    }
  }
}

// ---------------- merged pal@PV GEMM (bf16 out) ----------------
__global__ __launch_bounds__(256) void k_mm_pv(
    const unsigned short* __restrict__ pal, const unsigned short* __restrict__ W,
    const float* __restrict__ bias, unsigned short* __restrict__ CA,
    unsigned short* __restrict__ CE) {
  MM_PROLOG(4)
  const int o0 = bx * 128;
  const int br = bx >> 1;
  const unsigned short* Abf = pal + br * 128;
  u16x8 pw[2], pa_b[2];
  const unsigned short* Wb = W + (long)o0 * 128;
  #pragma unroll
  for (int p = 0; p < 2; ++p) {
    const int r = wrow + 64 * p;
    pw[p]   = *(const u16x8*)(Wb + (long)r * 128 + wslot * 8);
    pa_b[p] = *(const u16x8*)(Abf + (s0 + r) * 256 + wslot * 8);
  }
  for (int ch = 0; ch < 4; ++ch) {
    if (ch) __syncthreads();
    #pragma unroll
    for (int p = 0; p < 2; ++p) {
      const int r = wrow + 64 * p;
      const int ps = (wslot ^ XS(r)) * 8;
      *(u16x8*)&Ws[r * 32 + ps] = pw[p];
      *(u16x8*)&As[r * 32 + ps] = pa_b[p];
    }
    __syncthreads();
    if (ch + 1 < 4) {
      const int k0 = (ch + 1) * 32;
      #pragma unroll
      for (int p = 0; p < 2; ++p) {
        const int r = wrow + 64 * p;
        pw[p]   = *(const u16x8*)(Wb + (long)r * 128 + k0 + wslot * 8);
        pa_b[p] = *(const u16x8*)(Abf + (s0 + r) * 256 + k0 + wslot * 8);
      }
    }
    MM_MFMA_STEP
  }
  unsigned short* C = br ? CE : CA;
  const int ob = (bx & 1) * 128;
  #pragma unroll
  for (int n = 0; n < 4; ++n) {
    const float b = bias[o0 + wn + n * 16 + lr];
    #pragma unroll
    for (int m = 0; m < 4; ++m) {
      const long rowb = s0 + wm + m * 16 + lk * 4;
      #pragma unroll
      for (int r = 0; r < 4; ++r)
        C[(rowb + r) * 256 + ob + wn + n * 16 + lr] = f2bf(acc[m][n][r] + b);
    }
  }
}

// ---------------- GRU mega-GEMM v11: pair-unrolled chunks, 16 barriers ----------------
__global__ __launch_bounds__(512, 4) void k_gru11(
    const unsigned short* __restrict__ UB, const float* __restrict__ hid,
    const unsigned short* __restrict__ WF, const float* __restrict__ BG,
    float* __restrict__ hout) {
  __shared__ __align__(16) unsigned short As[4][4096];   // [pairbuf*2+sub][128x32]
  const int tid = threadIdx.x;                        // 0..511
  const int pid = blockIdx.y * 4 + blockIdx.x;        // grid (4,128)
  const int lin = pid >> 3;
  const int bx = lin & 3;
  const int by = (lin >> 2) * 8 + (pid & 7);          // 0..127
  const long s0 = (long)by * 128;
  const int wv = tid >> 6, l = tid & 63;
  const int sh = wv >> 2;                             // sample half
  const int cq = wv & 3;                              // col quad (== df)
  const int lr = l & 15, lk = l >> 4;
  const int row = tid >> 2;                           // 0..127
  const int q = tid & 3;
  const int sbase = row * 32 + ((q ^ XS(row)) * 8);

  f32x4 acc[4][4] = {};
  u16x8 bwc0, bwc1, bwc2, bwn0, bwn1, bwn2;
  u16x8 pa0, pa1;
  float4 pf0[2], pf1[2];

  // fragment base for (ch, n): WF + (((ch*4+bx)*4+cq)*4+n)*512 + l*8
  const unsigned short* WFb = WF + (((long)bx * 4 + cq) * 4) * 512 + l * 8;
#define WFRAG(CH, N) (*(const u16x8*)(WFb + ((long)(CH) * 64 + (N)) * 512))

#define G11_MFMA(BUF, G2)                                                     \
  {                                                                           \
    const unsigned short* AsC = As[BUF];                                      \
    bf16x8v af[4];                                                            \
    _Pragma("unroll")                                                         \
    for (int m = 0; m < 4; ++m) {                                             \
      const int r = sh * 64 + m * 16 + lr;                                    \
      af[m] = *(const bf16x8v*)&AsC[r * 32 + ((lk ^ XS(r)) * 8)];             \
    }                                                                         \
    _Pragma("unroll")                                                         \
    for (int m = 0; m < 4; ++m) {                                             \
      acc[m][0] = __builtin_amdgcn_mfma_f32_16x16x32_bf16(af[m], (bf16x8v)bwc0, acc[m][0], 0, 0, 0); \
      acc[m][1] = __builtin_amdgcn_mfma_f32_16x16x32_bf16(af[m], (bf16x8v)bwc1, acc[m][1], 0, 0, 0); \
      acc[m][G2] = __builtin_amdgcn_mfma_f32_16x16x32_bf16(af[m], (bf16x8v)bwc2, acc[m][G2], 0, 0, 0); \
    }                                                                         \
  }

  // prologue: stage pair 0 (chunks 0,1); W triple for chunk 0
  pa0 = *(const u16x8*)(UB + (s0 + row) * 768 + q * 8);
  pa1 = *(const u16x8*)(UB + (s0 + row) * 768 + 32 + q * 8);
  *(u16x8*)&As[0][sbase] = pa0;
  *(u16x8*)&As[1][sbase] = pa1;
  bwc0 = WFRAG(0, 0); bwc1 = WFRAG(0, 1); bwc2 = WFRAG(0, 2);
  __syncthreads();

  // u-part pairs 0..11 (chunks 0..23): gates {0,1,2}
  for (int p = 0; p < 12; ++p) {
    const int cur = (p & 1) * 2;
    // prefetch A for pair p+1 (full pair of chunks, 24-MFMA window)
    if (p + 1 < 12) {
      const int ka = (2 * p + 2) * 32;
      pa0 = *(const u16x8*)(UB + (s0 + row) * 768 + ka + q * 8);
      pa1 = *(const u16x8*)(UB + (s0 + row) * 768 + ka + 32 + q * 8);
    } else {
      const float* Af = hid + (s0 + row) * 256 + q * 8;
      pf0[0] = *(const float4*)(Af);      pf0[1] = *(const float4*)(Af + 4);
      pf1[0] = *(const float4*)(Af + 32); pf1[1] = *(const float4*)(Af + 36);
    }
    // chunk 2p: prefetch W for 2p+1, then MFMA
    bwn0 = WFRAG(2 * p + 1, 0); bwn1 = WFRAG(2 * p + 1, 1); bwn2 = WFRAG(2 * p + 1, 2);
    G11_MFMA(cur, 2)
    bwc0 = bwn0; bwc1 = bwn1; bwc2 = bwn2;
    // chunk 2p+1: prefetch W for next chunk, then MFMA
    if (p + 1 < 12) {
      bwn0 = WFRAG(2 * p + 2, 0); bwn1 = WFRAG(2 * p + 2, 1); bwn2 = WFRAG(2 * p + 2, 2);
    } else {
      bwn0 = WFRAG(24, 0); bwn1 = WFRAG(24, 1); bwn2 = WFRAG(24, 3);
    }
    G11_MFMA(cur + 1, 2)
    // stage pair p+1 into the other buffer pair
    {
      const int nxt = cur ^ 2;
      if (p + 1 < 12) {
        *(u16x8*)&As[nxt][sbase] = pa0;
        *(u16x8*)&As[nxt + 1][sbase] = pa1;
      } else {
        float fa[8];
        u16x8 pk;
        *(float4*)&fa[0] = pf0[0]; *(float4*)&fa[4] = pf0[1];
        #pragma unroll
        for (int i = 0; i < 8; ++i) pk[i] = f2bf(fa[i]);
        *(u16x8*)&As[nxt][sbase] = pk;
        *(float4*)&fa[0] = pf1[0]; *(float4*)&fa[4] = pf1[1];
        #pragma unroll
        for (int i = 0; i < 8; ++i) pk[i] = f2bf(fa[i]);
        *(u16x8*)&As[nxt + 1][sbase] = pk;
      }
    }
    __syncthreads();
    bwc0 = bwn0; bwc1 = bwn1; bwc2 = bwn2;
  }
  // hid-part pairs 12..15 (chunks 24..31): gates {0,1,3}
  for (int p = 12; p < 16; ++p) {
    const int cur = (p & 1) * 2;
    if (p + 1 < 16) {
      const int kma = (2 * (p + 1) - 24) * 32;
      const float* Af = hid + (s0 + row) * 256 + kma + q * 8;
      pf0[0] = *(const float4*)(Af);      pf0[1] = *(const float4*)(Af + 4);
      pf1[0] = *(const float4*)(Af + 32); pf1[1] = *(const float4*)(Af + 36);
    }
    // chunk 2p
    bwn0 = WFRAG(2 * p + 1, 0); bwn1 = WFRAG(2 * p + 1, 1); bwn2 = WFRAG(2 * p + 1, 3);
    G11_MFMA(cur, 3)
    bwc0 = bwn0; bwc1 = bwn1; bwc2 = bwn2;
    // chunk 2p+1
    if (p + 1 < 16) {
      bwn0 = WFRAG(2 * p + 2, 0); bwn1 = WFRAG(2 * p + 2, 1); bwn2 = WFRAG(2 * p + 2, 3);
    }
    G11_MFMA(cur + 1, 3)
    if (p + 1 < 16) {
      const int nxt = cur ^ 2;
      float fa[8];
      u16x8 pk;
      *(float4*)&fa[0] = pf0[0]; *(float4*)&fa[4] = pf0[1];
      #pragma unroll
      for (int i = 0; i < 8; ++i) pk[i] = f2bf(fa[i]);
      *(u16x8*)&As[nxt][sbase] = pk;
      *(float4*)&fa[0] = pf1[0]; *(float4*)&fa[4] = pf1[1];
      #pragma unroll
      for (int i = 0; i < 8; ++i) pk[i] = f2bf(fa[i]);
      *(u16x8*)&As[nxt + 1][sbase] = pk;
      __syncthreads();
      bwc0 = bwn0; bwc1 = bwn1; bwc2 = bwn2;
    }
  }

  // epilogue: acc[m][g], wave covers d = bx*64 + cq*16 + lr
  const int d = bx * 64 + cq * 16 + lr;
  const int bb = bx * 256 + cq * 64 + lr;
  const float bR  = BG[bb];
  const float bZ  = BG[bb + 16];
  const float bNi = BG[bb + 32];
  const float bNh = BG[bb + 48];
  #pragma unroll
  for (int m = 0; m < 4; ++m) {
    const long srow = s0 + sh * 64 + m * 16 + lk * 4;
    #pragma unroll
    for (int rr = 0; rr < 4; ++rr) {
      const long s = srow + rr;
      const float r_ = 1.f / (1.f + expf(-(acc[m][0][rr] + bR)));
      const float z_ = 1.f / (1.f + expf(-(acc[m][1][rr] + bZ)));
      const float n_ = tanhf(acc[m][2][rr] + bNi + r_ * (acc[m][3][rr] + bNh));
      const float hp = hid[s * 256 + d];
      hout[s * 256 + d] = (1.f - z_) * n_ + z_ * hp;
    }
  }
#undef G11_MFMA
#undef WFRAG
}

// ---------------- merged attention core (g bf16) ----------------
__global__ __launch_bounds__(256) void k_core2(
    const float* __restrict__ rawA, const float* __restrict__ rawE,
    const unsigned short* __restrict__ g, const float* __restrict__ gt_w,
    const float* __restrict__ gt_b, unsigned short* __restrict__ pal) {
  __shared__ float A_[4][15][36];
  __shared__ float E_[4][16][36];
  __shared__ float G_[4][8][32];
  __shared__ float P_[4][8][16];
  const int tid = threadIdx.x;
  const int w = tid >> 6, l = tid & 63;
  const long s = (long)blockIdx.x * 4 + w;

  const float* ra = rawA + s * 480;
  const float* re = rawE + s * 512;
  const unsigned short* gr = g + s * 256;
  #pragma unroll
  for (int i = l; i < 120; i += 64) {
    float4 v = *(const float4*)(ra + i * 4);
    *(float4*)&A_[w][i >> 3][(i & 7) * 4] = v;
  }
  #pragma unroll
  for (int i = l; i < 128; i += 64) {
    float4 v = *(const float4*)(re + i * 4);
    *(float4*)&E_[w][i >> 3][(i & 7) * 4] = v;
  }
  {
    u16x4 v = *(const u16x4*)(gr + l * 4);
    float4 f = { bf2f(v.x), bf2f(v.y), bf2f(v.z), bf2f(v.w) };
    *(float4*)&G_[w][l >> 3][(l & 7) * 4] = f;
  }
  __syncthreads();

  bool mv = false;
  if (l < 15) {
    #pragma unroll
    for (int c = 0; c < 8; ++c) {
      float4 x = *(const float4*)&A_[w][l][c * 4];
      mv |= (x.x != 0.f) | (x.y != 0.f) | (x.z != 0.f) | (x.w != 0.f);
    }
  } else if (l >= 16 && l < 32) {
    #pragma unroll
    for (int c = 0; c < 8; ++c) {
      float4 x = *(const float4*)&E_[w][l - 16][c * 4];
      mv |= (x.x != 0.f) | (x.y != 0.f) | (x.z != 0.f) | (x.w != 0.f);
    }
  }
  unsigned long long bal = __ballot(mv);
  unsigned mA = (unsigned)bal & 0x7FFFu;
  unsigned mE = (unsigned)(bal >> 16) & 0xFFFFu;
  float xa = gt_w[0] * log1pf((float)__popc(mA)) + gt_b[0];
  float spa = fmaxf(xa, 0.f) + log1pf(expf(-fabsf(xa)));
  float scaleA = 1.f / (8.f * (spa + 1.f));
  float xe = gt_w[1] * log1pf((float)__popc(mE)) + gt_b[1];
  float spe = fmaxf(xe, 0.f) + log1pf(expf(-fabsf(xe)));
  float scaleE = 1.f / (8.f * (spe + 1.f));

  {
    const int h = l >> 4, n = l & 15;
    const bool okA = (n < 15) && ((mA >> n) & 1);
    const bool okE = (mE >> n) & 1;
    const float* arow = &A_[w][n < 15 ? n : 0][0];
    const float* erow = &E_[w][n][0];
    const float* garow = &G_[w][h][0];
    const float* gerow = &G_[w][4 + h][0];
    float accA = 0.f, accE = 0.f;
    #pragma unroll
    for (int j = 0; j < 32; ++j) {
      accA = fmaf(garow[j], arow[j], accA);
      accE = fmaf(gerow[j], erow[j], accE);
    }
    float sA = okA ? accA * scaleA : -INFINITY;
    float sE = okE ? accE * scaleE : -INFINITY;
    float mAx = sA, mEx = sE;
    #pragma unroll
    for (int off = 8; off; off >>= 1) {
      mAx = fmaxf(mAx, __shfl_xor(mAx, off));
      mEx = fmaxf(mEx, __shfl_xor(mEx, off));
    }
    float eA = okA ? expf(sA - mAx) : 0.f;
    float eE = okE ? expf(sE - mEx) : 0.f;
    float suA = eA, suE = eE;
    #pragma unroll
    for (int off = 8; off; off >>= 1) {
      suA += __shfl_xor(suA, off);
      suE += __shfl_xor(suE, off);
    }
    P_[w][h][n] = eA / suA;
    P_[w][4 + h][n] = eE / suE;
  }
  __syncthreads();

  {
    const int j = l & 31, hh = l >> 5;
    unsigned short* po = pal + s * 256 + hh * 32 + j;
    #pragma unroll
    for (int r = 0; r < 2; ++r) {
      const int ha = r * 2 + hh;
      float a0 = 0.f, a1 = 0.f;
      #pragma unroll
      for (int n = 0; n < 15; ++n)
        a0 = fmaf(P_[w][ha][n], A_[w][n][j], a0);
      #pragma unroll
      for (int n = 0; n < 16; ++n)
        a1 = fmaf(P_[w][4 + ha][n], E_[w][n][j], a1);
      po[r * 64] = f2bf(a0);
      po[128 + r * 64] = f2bf(a1);
    }
  }
}

// ---------------- fused CLN+CLN+LN3 -> u (all bf16 inputs) ----------------
__global__ __launch_bounds__(256) void k_clnln(
    const unsigned short* __restrict__ aA, const unsigned short* __restrict__ aE,
    const unsigned short* __restrict__ qsb, const unsigned short* __restrict__ gbb,
    const float* __restrict__ g, const float* __restrict__ b,
    unsigned short* __restrict__ UB) {
  int w = threadIdx.x >> 6, l = threadIdx.x & 63;
  long s = (long)blockIdx.x * 4 + w;
  int d = l * 4;
  u16x4 av = *(const u16x4*)(aA + s * 256 + d);
  u16x4 ev = *(const u16x4*)(aE + s * 256 + d);
  u16x4 qv = *(const u16x4*)(qsb + s * 256 + d);
  float4 vA = { bf2f(av.x), bf2f(av.y), bf2f(av.z), bf2f(av.w) };
  float4 vE = { bf2f(ev.x), bf2f(ev.y), bf2f(ev.z), bf2f(ev.w) };
  float4 vq = { bf2f(qv.x), bf2f(qv.y), bf2f(qv.z), bf2f(qv.w) };
  const unsigned short* gbr = gbb + s * 1024;
  float sumA = vA.x + vA.y + vA.z + vA.w;
  float ssqA = vA.x*vA.x + vA.y*vA.y + vA.z*vA.z + vA.w*vA.w;
  float sumE = vE.x + vE.y + vE.z + vE.w;
  float ssqE = vE.x*vE.x + vE.y*vE.y + vE.z*vE.z + vE.w*vE.w;
  #pragma unroll
  for (int off = 32; off > 0; off >>= 1) {
    sumA += __shfl_xor(sumA, off); ssqA += __shfl_xor(ssqA, off);
    sumE += __shfl_xor(sumE, off); ssqE += __shfl_xor(ssqE, off);
  }
  float muA = sumA * (1.f / 256.f);
  float rstdA = rsqrtf(ssqA * (1.f / 256.f) - muA * muA + 1e-5f);
  float muE = sumE * (1.f / 256.f);
  float rstdE = rsqrtf(ssqE * (1.f / 256.f) - muE * muE + 1e-5f);

  u16x4 u0 = *(const u16x4*)(gbr + d);
  u16x4 u1 = *(const u16x4*)(gbr + 256 + d);
  u16x4 u2 = *(const u16x4*)(gbr + 512 + d);
  u16x4 u3 = *(const u16x4*)(gbr + 768 + d);
  float4 gA4 = { bf2f(u0.x), bf2f(u0.y), bf2f(u0.z), bf2f(u0.w) };
  float4 bA4 = { bf2f(u1.x), bf2f(u1.y), bf2f(u1.z), bf2f(u1.w) };
  float4 gE4 = { bf2f(u2.x), bf2f(u2.y), bf2f(u2.z), bf2f(u2.w) };
  float4 bE4 = { bf2f(u3.x), bf2f(u3.y), bf2f(u3.z), bf2f(u3.w) };
  float4 zA, zE;
  zA.x = (1.f + gA4.x) * ((vA.x - muA) * rstdA) + bA4.x;
  zA.y = (1.f + gA4.y) * ((vA.y - muA) * rstdA) + bA4.y;
  zA.z = (1.f + gA4.z) * ((vA.z - muA) * rstdA) + bA4.z;
  zA.w = (1.f + gA4.w) * ((vA.w - muA) * rstdA) + bA4.w;
  zE.x = (1.f + gE4.x) * ((vE.x - muE) * rstdE) + bE4.x;
  zE.y = (1.f + gE4.y) * ((vE.y - muE) * rstdE) + bE4.y;
  zE.z = (1.f + gE4.z) * ((vE.z - muE) * rstdE) + bE4.z;
  zE.w = (1.f + gE4.w) * ((vE.w - muE) * rstdE) + bE4.w;

  float sum = vq.x+vq.y+vq.z+vq.w + zA.x+zA.y+zA.z+zA.w + zE.x+zE.y+zE.z+zE.w;
  float ssq = vq.x*vq.x+vq.y*vq.y+vq.z*vq.z+vq.w*vq.w
            + zA.x*zA.x+zA.y*zA.y+zA.z*zA.z+zA.w*zA.w
            + zE.x*zE.x+zE.y*zE.y+zE.z*zE.z+zE.w*zE.w;
  #pragma unroll
  for (int off = 32; off > 0; off >>= 1) {
    sum += __shfl_xor(sum, off); ssq += __shfl_xor(ssq, off);
  }
  float mu = sum * (1.f / 768.f);
  float rstd = rsqrtf(ssq * (1.f / 768.f) - mu * mu + 1e-5f);

  float4 g0 = *(const float4*)(g + d),       b0 = *(const float4*)(b + d);
  float4 g1 = *(const float4*)(g + 256 + d), b1 = *(const float4*)(b + 256 + d);
  float4 g2 = *(const float4*)(g + 512 + d), b2 = *(const float4*)(b + 512 + d);
  unsigned short* ur = UB + s * 768;
  u16x4 o;
  o.x = f2bf((vq.x - mu) * rstd * g0.x + b0.x);
  o.y = f2bf((vq.y - mu) * rstd * g0.y + b0.y);
  o.z = f2bf((vq.z - mu) * rstd * g0.z + b0.z);
  o.w = f2bf((vq.w - mu) * rstd * g0.w + b0.w);
  *(u16x4*)&ur[d] = o;
  o.x = f2bf((zA.x - mu) * rstd * g1.x + b1.x);
  o.y = f2bf((zA.y - mu) * rstd * g1.y + b1.y);
  o.z = f2bf((zA.z - mu) * rstd * g1.z + b1.z);
  o.w = f2bf((zA.w - mu) * rstd * g1.w + b1.w);
  *(u16x4*)&ur[256 + d] = o;
  o.x = f2bf((zE.x - mu) * rstd * g2.x + b2.x);
  o.y = f2bf((zE.y - mu) * rstd * g2.y + b2.y);
  o.z = f2bf((zE.z - mu) * rstd * g2.z + b2.z);
  o.w = f2bf((zE.w - mu) * rstd * g2.w + b2.w);
  *(u16x4*)&ur[512 + d] = o;
}

// ---------------- fused heads: 64-sample blocks ----------------
__global__ __launch_bounds__(256) void k_headsmm(
    const float* __restrict__ h, const unsigned short* __restrict__ WHD,
    const float* __restrict__ BHD, const float* __restrict__ eraw,
    const float* __restrict__ log_tau, float* __restrict__ Qout) {
  __shared__ __align__(16) unsigned short As[2048];   // 64 x 32
  __shared__ __align__(16) unsigned short Ws[2048];   // 64 x 32
  __shared__ float obs[64][49];
  const int tid = threadIdx.x;
  const long s0 = (long)blockIdx.x * 64;
  const int wv = tid >> 6, l = tid & 63;
  const int lr = l & 15, lk = l >> 4;
  const int row = tid >> 2;
  const int q = tid & 3;
  f32x4 acc[4] = {};
  u16x8 pw;
  float4 pa_f[2];
  pw = *(const u16x8*)(WHD + (long)row * 256 + q * 8);
  {
    const float* Af = h + (s0 + row) * 256 + q * 8;
    pa_f[0] = *(const float4*)(Af);
    pa_f[1] = *(const float4*)(Af + 4);
  }
  for (int ch = 0; ch < 8; ++ch) {
    if (ch) __syncthreads();
    *(u16x8*)&Ws[row * 32 + ((q ^ XS(row)) * 8)] = pw;
    {
      float fa[8];
      *(float4*)&fa[0] = pa_f[0];
      *(float4*)&fa[4] = pa_f[1];
      u16x8 pk;
      #pragma unroll
      for (int i = 0; i < 8; ++i) pk[i] = f2bf(fa[i]);
      *(u16x8*)&As[row * 32 + ((q ^ XS(row)) * 8)] = pk;
    }
    __syncthreads();
    if (ch + 1 < 8) {
      const int k0 = (ch + 1) * 32;
      pw = *(const u16x8*)(WHD + (long)row * 256 + k0 + q * 8);
      const float* Af = h + (s0 + row) * 256 + k0 + q * 8;
      pa_f[0] = *(const float4*)(Af);
      pa_f[1] = *(const float4*)(Af + 4);
    }
    {
      bf16x8v af, bw[4];
      {
        const int r = wv * 16 + lr;
        af = *(const bf16x8v*)&As[r * 32 + ((lk ^ XS(r)) * 8)];
      }
      #pragma unroll
      for (int n = 0; n < 4; ++n) {
        const int r = n * 16 + lr;
        bw[n] = *(const bf16x8v*)&Ws[r * 32 + ((lk ^ XS(r)) * 8)];
      }
      #pragma unroll
      for (int n = 0; n < 4; ++n)
        acc[n] = __builtin_amdgcn_mfma_f32_16x16x32_bf16(af, bw[n], acc[n], 0, 0, 0);
    }
  }
  #pragma unroll
  for (int n = 0; n < 3; ++n) {
    const int col = n * 16 + lr;
    const float b = BHD[col];
    const int rowo = wv * 16 + lk * 4;
    #pragma unroll
    for (int rr = 0; rr < 4; ++rr)
      obs[rowo + rr][col] = acc[n][rr] + b;
  }
  __syncthreads();
  const float itm = 1.f / (expf(log_tau[0]) + 1e-6f);
  const float its = 1.f / (expf(log_tau[1]) + 1e-6f);
  for (int rep = 0; rep < 4; ++rep) {
    const int sloc = rep * 16 + (tid >> 4);
    const int i = tid & 15;
    const long s = s0 + sloc;
    const float V = obs[sloc][0];
    const float* er = eraw + s * 512 + i * 32;
    bool valid = false; float a0 = 0.f;
    #pragma unroll
    for (int jb = 0; jb < 8; ++jb) {
      float4 e4 = *(const float4*)(er + jb * 4);
      valid |= (e4.x != 0.f) | (e4.y != 0.f) | (e4.z != 0.f) | (e4.w != 0.f);
      a0 += obs[sloc][9 + jb * 4 + 0] * e4.x + obs[sloc][9 + jb * 4 + 1] * e4.y +
            obs[sloc][9 + jb * 4 + 2] * e4.z + obs[sloc][9 + jb * 4 + 3] * e4.w;
    }
    float a = (a0 + obs[sloc][41]) * 0.0625f;
    float sa = valid ? a : 0.f;
    float cv = valid ? 1.f : 0.f;
    #pragma unroll
    for (int off = 8; off > 0; off >>= 1) {
      sa += __shfl_xor(sa, off);
      cv += __shfl_xor(cv, off);
    }
    float me = sa / fmaxf(cv, 1.f);
    Qout[s * 22 + 6 + i] = V + obs[sloc][2] + (valid ? (a - me) * its : -1e30f * its);
    if (i < 6) {
      float mean = 0.f;
      #pragma unroll
      for (int t = 0; t < 6; ++t) mean += obs[sloc][3 + t];
      mean *= (1.f / 6.f);
      Qout[s * 22 + i] = V + obs[sloc][1] + (obs[sloc][3 + i] - mean) * 0.0625f * itm;
    }
  }
}

// ---------------- launch ----------------
extern "C" void kernel_launch(void* const* d_in, const int* in_sizes, int n_in,
                              void* d_out, int out_size, void* d_ws, size_t ws_size,
                              hipStream_t stream) {
  const float* own_raw   = (const float*)d_in[0];
  const float* ally_raw  = (const float*)d_in[1];
  const float* enemy_raw = (const float*)d_in[2];
  const float* hidden    = (const float*)d_in[3];
  const float* W_own     = (const float*)d_in[4];
  const float* b_own     = (const float*)d_in[5];
  const float* W_ally    = (const float*)d_in[6];
  const float* b_ally    = (const float*)d_in[7];
  const float* W_enemy   = (const float*)d_in[8];
  const float* b_enemy   = (const float*)d_in[9];
  const float* gt_w      = (const float*)d_in[10];
  const float* gt_b      = (const float*)d_in[11];
  const float* attnA_W   = (const float*)d_in[12];
  const float* attnA_b   = (const float*)d_in[13];
  const float* attnE_W   = (const float*)d_in[14];
  const float* attnE_b   = (const float*)d_in[15];
  const float* clnA_W    = (const float*)d_in[16];
  const float* clnA_b    = (const float*)d_in[17];
  const float* clnE_W    = (const float*)d_in[18];
  const float* clnE_b    = (const float*)d_in[19];
  const float* ln3_g     = (const float*)d_in[20];
  const float* ln3_b     = (const float*)d_in[21];
  const float* gru_Wih   = (const float*)d_in[22];
  const float* gru_Whh   = (const float*)d_in[23];
  const float* gru_bih   = (const float*)d_in[24];
  const float* gru_bhh   = (const float*)d_in[25];
  const float* Wv_head   = (const float*)d_in[26];
  const float* bv_head   = (const float*)d_in[27];
  const float* Wtb       = (const float*)d_in[28];
  const float* btb       = (const float*)d_in[29];
  const float* log_tau   = (const float*)d_in[30];
  const float* Wmq       = (const float*)d_in[31];
  const float* bmq       = (const float*)d_in[32];
  const float* protos    = (const float*)d_in[33];
  const float* Wqs       = (const float*)d_in[34];
  const float* bqs       = (const float*)d_in[35];
  const float* Wke       = (const float*)d_in[36];
  const float* bke       = (const float*)d_in[37];

  float* ws  = (float*)d_ws;
  float* out = (float*)d_out;
  float* hout = out + HOFF;
  unsigned short* WB   = (unsigned short*)hout;
  unsigned short* qsb  = (unsigned short*)(ws + BUF2_OFF);
  unsigned short* palb = (unsigned short*)(ws + QSRC_OFF);
  unsigned short* WHD  = (unsigned short*)ws;
  unsigned short* wfrag = (unsigned short*)(ws + BUF1_OFF);  // WF (after core2)
  unsigned short* gb16 = (unsigned short*)(ws + GBUF_OFF);   // g bf16
  unsigned short* aoA  = (unsigned short*)(ws + AOUTA_OFF);  // aout bf16
  unsigned short* aoE  = (unsigned short*)(ws + AOUTE_OFF);
  unsigned short* gbb  = (unsigned short*)(ws + GBB_OFF);
  unsigned short* ub   = (unsigned short*)(ws + UB_OFF);     // u bf16

  k_fuseA<<<576, 256, 0, stream>>>(attnA_W, attnA_b, attnE_W, attnE_b,
                                   W_ally, b_ally, W_enemy, b_enemy, Wke, bke,
                                   clnA_W, clnE_W, ws, WB);
  k_fuseB<<<599, 256, 0, stream>>>(protos, Wmq, bmq, Wqs, bqs,
                                   attnA_W, attnA_b, attnE_W, attnE_b,
                                   clnA_b, clnE_b, ws, WB);
  k_fuse4<<<129, 256, 0, stream>>>(Wv_head, bv_head, Wtb, btb, ws, WHD);

  // q_src bf16
  k_densek<30, 256><<<dim3(BN/64, 4), 256, 0, stream>>>(own_raw, W_own, b_own, qsb);

  // merged: g bf16 (256) + gamma/beta bf16 (1024)
  k_mm_qs<<<dim3(10, 128), 256, 0, stream>>>(qsb, WB, ws + BMG_OFF, gb16, gbb);

  // merged attention core -> pal (bf16)
  k_core2<<<BN/4, 256, 0, stream>>>(ally_raw, enemy_raw, gb16, gt_w, gt_b, palb);

  // GRU fragment-order weights (into BUF1, now dead)
  k_gruw2<<<516, 256, 0, stream>>>(gru_Wih, gru_Whh, gru_bih, gru_bhh,
                                   wfrag, ws + BGRU_OFF);

  // aout = pal @ PV + bpj (both branches, bf16 out)
  k_mm_pv<<<dim3(4, 128), 256, 0, stream>>>(palb, WB + PJA_S, ws + BPJA_OFF,
                                            aoA, aoE);

  // fused cln+cln+ln3 -> u bf16
  k_clnln<<<BN/4, 256, 0, stream>>>(aoA, aoE, qsb, gbb, ln3_g, ln3_b, ub);

  // GRU mega-GEMM v11 -> h (pair-unrolled chunks, 16 barriers, W fragments direct)
  k_gru11<<<dim3(4, 128), 512, 0, stream>>>(ub, hidden, wfrag, ws + BGRU_OFF, hout);

  // fused heads GEMM + epilogue -> Q
  k_headsmm<<<BN/64, 256, 0, stream>>>(hout, WHD, ws + BHD_OFF, enemy_raw,
                                       log_tau, out);
}